// Round 18
// baseline (415.368 us; speedup 1.0000x reference)
//
#include <hip/hip_runtime.h>

// GCN(3 layers) + MLP(4 layers), N=50000, E=800000, out = N x 8 bf16.
// NOTE: do NOT include <hip/hip_bf16.h> — breaks this harness's build
// (rounds 1-4 fell back to a stub; round 5 proved it). Manual bf16 ushort ops.
// Dtype runtime-detection: flagI (edge_index int64 vs int32), flagF (floats
// fp32 vs packed bf16).
//
// R18: agg+GEMM fused per GCN layer (6 dispatches -> 3). agg->GEMM is
// row-local (C[i,:] = aggrow(i) @ W), so each wave aggregates its 16 rows
// into wave-private LDS (no barrier: MFMA A-row m=lane&15 belongs to the
// same wave) then runs the MFMA with affine+ReLU epilogue. Kills the bufC
// 9.5MB-write + 9.6MB-read round trip per layer and 3 launch gaps.
// LDS strides 104/72 shorts -> 52/36 words: 2-way bank aliasing only (free).
// agg96 gather itself is at its structural floor (FETCH ~70MB = 8 XCD x H;
// random sources). Partition-sort CSR + fused MLP kept from R17.

#define GN 50000
#define GE 800000
#define NPART 98        // partitions of 512 dst nodes
#define PSLOT 9216      // slab capacity per partition (mean 8163, +11 sigma)
#define CHK 2048        // edges per block in pass 1

typedef __attribute__((ext_vector_type(8))) short bf16x8;
typedef __attribute__((ext_vector_type(4))) float floatx4;

__device__ __forceinline__ float ar1_b2f(unsigned short h) {
    return __uint_as_float(((unsigned)h) << 16);
}
__device__ __forceinline__ unsigned short ar1_f2b(float f) {
    unsigned u = __float_as_uint(f);
    u = u + 0x7FFFu + ((u >> 16) & 1u);   // round-to-nearest-even
    return (unsigned short)(u >> 16);
}

// block 0: flagI (edge_index int64 <=> odd words ~all zero) + zero gcur
// block 1: flagF (floats fp32 vs packed bf16; see R6 notes)
__global__ void ar1_detect(const int* ei, const unsigned short* xw,
                           int* flagI, int* flagF, int* gcur) {
    __shared__ int cnt;
    if (threadIdx.x == 0) cnt = 0;
    __syncthreads();
    if (blockIdx.x == 0) {
        if ((int)threadIdx.x < NPART) gcur[threadIdx.x] = 0;
        if (ei[2 * threadIdx.x + 1] != 0) atomicAdd(&cnt, 1);
        __syncthreads();
        if (threadIdx.x == 0) flagI[0] = (cnt < 8) ? 1 : 0;
    } else {
        unsigned short w = xw[2 * threadIdx.x];
        int ex = (w >> 7) & 0xFF;
        if (w == 0 || (ex >= 90 && ex <= 150)) atomicAdd(&cnt, 1);
        __syncthreads();
        if (threadIdx.x == 0) flagF[0] = (cnt > 200) ? 0 : 1;
    }
}

// pass 1: partition edges into 98 slabs; packed word = s | (d&511)<<17
__global__ __launch_bounds__(256)
void ar1_part(const int* __restrict__ ei, const int* __restrict__ flagI,
              int* __restrict__ gcur, unsigned int* __restrict__ pairs, int E) {
    __shared__ int cnt[NPART], base[NPART], cur[NPART];
    int tid = (int)threadIdx.x;
    for (int i = tid; i < NPART; i += 256) { cnt[i] = 0; cur[i] = 0; }
    __syncthreads();
    int is64 = flagI[0];
    int e0 = (int)blockIdx.x * CHK;
    unsigned pk[8]; int q[8];
#pragma unroll
    for (int k = 0; k < 8; k++) {
        int e = e0 + k * 256 + tid;
        q[k] = -1; pk[k] = 0;
        if (e < E) {
            int s = is64 ? ei[2 * e] : ei[e];
            int d = is64 ? ei[2 * (E + e)] : ei[E + e];
            if ((unsigned)s < (unsigned)GN && (unsigned)d < (unsigned)GN) {
                int qq = d >> 9;
                q[k] = qq;
                pk[k] = (unsigned)s | ((unsigned)(d & 511) << 17);
                atomicAdd(&cnt[qq], 1);
            }
        }
    }
    __syncthreads();
    for (int i = tid; i < NPART; i += 256)
        base[i] = (cnt[i] > 0) ? atomicAdd(&gcur[i], cnt[i]) : 0;
    __syncthreads();
#pragma unroll
    for (int k = 0; k < 8; k++) {
        if (q[k] >= 0) {
            int r = base[q[k]] + atomicAdd(&cur[q[k]], 1);
            if (r < PSLOT) pairs[(size_t)q[k] * PSLOT + r] = pk[k];
        }
    }
}

// exclusive scan of partition sizes -> global CSR base per partition
__global__ void ar1_pscan(const int* gcur, int* pbase) {
    __shared__ int sm[128];
    int tid = (int)threadIdx.x;   // 128
    int v = (tid < NPART) ? gcur[tid] : 0;
    sm[tid] = v;
    __syncthreads();
    for (int off = 1; off < 128; off <<= 1) {
        int t = (tid >= off) ? sm[tid - off] : 0;
        __syncthreads();
        sm[tid] += t;
        __syncthreads();
    }
    if (tid < NPART) pbase[tid] = sm[tid] - v;
}

// pass 2: per-partition -> contiguous CSR slice + indeg/offs/dinv
__global__ __launch_bounds__(256)
void ar1_csr(const unsigned int* __restrict__ pairs, const int* __restrict__ gcur,
             const int* __restrict__ pbase, int* __restrict__ csr,
             int* __restrict__ indeg, int* __restrict__ offs,
             float* __restrict__ dinv) {
    __shared__ int ncnt[512], pre[512], cur[512], psum[16];
    int p = (int)blockIdx.x, tid = (int)threadIdx.x;
    int cntE = gcur[p];
    if (cntE > PSLOT) cntE = PSLOT;
    int gbase = pbase[p];
    for (int i = tid; i < 512; i += 256) ncnt[i] = 0;
    __syncthreads();
    const unsigned int* pp = pairs + (size_t)p * PSLOT;
    for (int i = tid; i < cntE; i += 256) atomicAdd(&ncnt[pp[i] >> 17], 1);
    __syncthreads();
    if (tid < 16) {
        int s = 0;
        for (int j = tid * 32; j < tid * 32 + 32; j++) { pre[j] = s; s += ncnt[j]; }
        psum[tid] = s;
    }
    __syncthreads();
    if (tid == 0) {
        int s = 0;
        for (int j = 0; j < 16; j++) { int t = psum[j]; psum[j] = s; s += t; }
    }
    __syncthreads();
    if (tid < 16)
        for (int j = tid * 32; j < tid * 32 + 32; j++) pre[j] += psum[tid];
    __syncthreads();
    for (int j = tid; j < 512; j += 256) {
        cur[j] = pre[j];
        int node = p * 512 + j;
        if (node < GN) {
            indeg[node] = ncnt[j];
            offs[node] = gbase + pre[j];
            dinv[node] = rsqrtf((float)(ncnt[j] + 1));   // +1: self loop
        }
    }
    __syncthreads();
    for (int i = tid; i < cntE; i += 256) {
        unsigned v = pp[i];
        int r = atomicAdd(&cur[v >> 17], 1);
        csr[gbase + r] = (int)(v & 0x1FFFFu);
    }
}

struct PackAll {
    const void* src[7];
    unsigned short* dst[7];
    int K[7], M[7], start[8];
};
struct SmallCvt {
    const void* src[4];   // lb1, lb2, lb3, lb4
    float* dst[4];
    int n[4];
    const void* gb[9];    // b1,g1,be1, b2,g2,be2, b3,g3,be3
    float* ss[6];         // scale1,shift1, ...
};

// fused weight prep (carries the harness kernel name):
// blocks 0..44: pack 4 fragments each into MFMA B order (178 frags total);
// block 45: small-vector cvt + GCN bias/BN fold (scale=C*g, shift=b*C*g+be).
__global__ void Arthur1_16458314678864_kernel(PackAll pa, SmallCvt sc,
                                              const int* flagF) {
    int b = (int)blockIdx.x;
    int f = flagF[0];
    if (b < 45) {
        int frag_g = b * 4 + ((int)threadIdx.x >> 6);
        if (frag_g >= 178) return;
        int w = 0;
        while (w < 6 && frag_g >= pa.start[w + 1]) w++;
        int frag = frag_g - pa.start[w];
        int K = pa.K[w], M = pa.M[w];
        int lane = (int)threadIdx.x & 63;
        int nch = K >> 5;
        int t = frag / nch, c = frag - t * nch;
        int n = t * 16 + (lane & 15);
        int k0 = c * 32 + (lane >> 4) * 8;
        unsigned short* o = pa.dst[w] + ((size_t)frag * 64 + lane) * 8;
        for (int j = 0; j < 8; j++) {
            unsigned short v = 0;
            if (n < M) {
                int idx = (k0 + j) * M + n;
                v = f ? ar1_f2b(((const float*)pa.src[w])[idx])
                      : ((const unsigned short*)pa.src[w])[idx];
            }
            o[j] = v;
        }
    } else {
        const float C = 0.9999950000374997f;   // 1/sqrt(1+1e-5)
        for (int s = 0; s < 4; s++) {
            for (int i = threadIdx.x; i < sc.n[s]; i += 256) {
                float v = f ? ((const float*)sc.src[s])[i]
                            : ar1_b2f(((const unsigned short*)sc.src[s])[i]);
                sc.dst[s][i] = v;
            }
        }
        for (int k = 0; k < 3; k++) {
            for (int i = threadIdx.x; i < 96; i += 256) {
                float bb, g, be;
                if (f) {
                    bb = ((const float*)sc.gb[3 * k + 0])[i];
                    g  = ((const float*)sc.gb[3 * k + 1])[i];
                    be = ((const float*)sc.gb[3 * k + 2])[i];
                } else {
                    bb = ar1_b2f(((const unsigned short*)sc.gb[3 * k + 0])[i]);
                    g  = ar1_b2f(((const unsigned short*)sc.gb[3 * k + 1])[i]);
                    be = ar1_b2f(((const unsigned short*)sc.gb[3 * k + 2])[i]);
                }
                sc.ss[2 * k + 0][i] = C * g;
                sc.ss[2 * k + 1][i] = bb * C * g + be;
            }
        }
    }
}

// ---------------- fused layer 1: agg over x (64-dim) + GEMM 64->96 ----------
// Block = 64 nodes, 4 waves x 16 nodes. Phase 1: wave gathers its 16 rows
// into wave-private LDS (stride 72 shorts = 36 words: 2-way banks, free).
// Phase 2: MFMA K=64 (nch=2, NT=6) + affine/ReLU -> C stride 96. No barrier.
__global__ __launch_bounds__(256, 8)
void ar1_ag64(const void* __restrict__ Xv, const int* __restrict__ offs,
              const int* __restrict__ indeg, const int* __restrict__ csr,
              const float* __restrict__ dinv, const int* __restrict__ flagF,
              const unsigned short* __restrict__ Bp,
              const float* __restrict__ scale, const float* __restrict__ shift,
              unsigned short* __restrict__ C) {
    __shared__ unsigned short AL[64 * 72];
    int tid = (int)threadIdx.x, wv = tid >> 6, lane = tid & 63;
    int nb = (int)blockIdx.x * 64;
    int f = flagF[0];
    const unsigned short* X16 = (const unsigned short*)Xv;
    const float* X32 = (const float*)Xv;
    int chunk = lane & 7;      // feats chunk*8 .. +8
    int eslot = lane >> 3;     // 0..7

    for (int t = 0; t < 16; t++) {
        int node = nb + wv * 16 + t;
        if (node >= GN) break;
        float di = dinv[node];
        int off = offs[node], cnt = indeg[node];
        float acc[8];
#pragma unroll
        for (int j = 0; j < 8; j++) acc[j] = 0.f;

        for (int base = 0; base < cnt; base += 16) {
            int ss[2]; float ww[2];
#pragma unroll
            for (int k = 0; k < 2; k++) {
                int e = base + k * 8 + eslot;
                int s = node; float w = 0.f;
                if (e < cnt) {
                    s = csr[off + e];
                    if ((unsigned)s >= (unsigned)GN) s = node;
                    w = dinv[s] * di;
                }
                ss[k] = s; ww[k] = w;
            }
#pragma unroll
            for (int k = 0; k < 2; k++) {
                float hv[8];
                if (f) {
                    floatx4 a = *((const floatx4*)(X32 + (size_t)ss[k] * 64 + chunk * 8));
                    floatx4 b = *((const floatx4*)(X32 + (size_t)ss[k] * 64 + chunk * 8 + 4));
#pragma unroll
                    for (int j = 0; j < 4; j++) { hv[j] = a[j]; hv[4 + j] = b[j]; }
                } else {
                    bf16x8 h = *((const bf16x8*)(X16 + (size_t)ss[k] * 64 + chunk * 8));
#pragma unroll
                    for (int j = 0; j < 8; j++) hv[j] = ar1_b2f((unsigned short)h[j]);
                }
#pragma unroll
                for (int j = 0; j < 8; j++) acc[j] += ww[k] * hv[j];
            }
        }

#pragma unroll
        for (int j = 0; j < 8; j++) {
            acc[j] += __shfl_xor(acc[j], 8, 64);
            acc[j] += __shfl_xor(acc[j], 16, 64);
            acc[j] += __shfl_xor(acc[j], 32, 64);
        }

        if (eslot == 0) {
            float hv[8];
            if (f) {
                floatx4 a = *((const floatx4*)(X32 + (size_t)node * 64 + chunk * 8));
                floatx4 b = *((const floatx4*)(X32 + (size_t)node * 64 + chunk * 8 + 4));
#pragma unroll
                for (int j = 0; j < 4; j++) { hv[j] = a[j]; hv[4 + j] = b[j]; }
            } else {
                bf16x8 h = *((const bf16x8*)(X16 + (size_t)node * 64 + chunk * 8));
#pragma unroll
                for (int j = 0; j < 8; j++) hv[j] = ar1_b2f((unsigned short)h[j]);
            }
            bf16x8 o;
#pragma unroll
            for (int j = 0; j < 8; j++)
                o[j] = (short)ar1_f2b(acc[j] + di * di * hv[j]);
            *((bf16x8*)(AL + (size_t)(wv * 16 + t) * 72 + chunk * 8)) = o;
        }
    }

    // phase 2: MFMA from wave-private LDS rows (same wave wrote them)
    int m = lane & 15, quad = lane >> 4;
    floatx4 acc[6];
#pragma unroll
    for (int t = 0; t < 6; t++) acc[t] = (floatx4){0.f, 0.f, 0.f, 0.f};
#pragma unroll
    for (int c = 0; c < 2; c++) {
        bf16x8 a = *((const bf16x8*)(AL + (size_t)(wv * 16 + m) * 72 + c * 32 + quad * 8));
#pragma unroll
        for (int t = 0; t < 6; t++) {
            bf16x8 b = *((const bf16x8*)(Bp + ((size_t)(t * 2 + c) * 64 + lane) * 8));
            acc[t] = __builtin_amdgcn_mfma_f32_16x16x32_bf16(a, b, acc[t], 0, 0, 0);
        }
    }
#pragma unroll
    for (int t = 0; t < 6; t++) {
#pragma unroll
        for (int r = 0; r < 4; r++) {
            int row = nb + wv * 16 + quad * 4 + r;
            int col = t * 16 + m;
            if (row < GN) {
                float v = acc[t][r] * scale[col] + shift[col];
                C[(size_t)row * 96 + col] = ar1_f2b(fmaxf(v, 0.f));
            }
        }
    }
}

// ---------------- fused layers 2/3: agg (96-dim) + GEMM 96->96 --------------
// Phase 1: 4 eslots x 12 chunks (48 active lanes), 4x edge unroll; rows into
// wave-private LDS (stride 104 shorts = 52 words: 2-way banks, free).
// Phase 2: MFMA K=96 (nch=3, NT=6) + affine/ReLU -> C stride 96.
__global__ __launch_bounds__(256, 8)
void ar1_ag96(const unsigned short* __restrict__ H, const int* __restrict__ offs,
              const int* __restrict__ indeg, const int* __restrict__ csr,
              const float* __restrict__ dinv,
              const unsigned short* __restrict__ Bp,
              const float* __restrict__ scale, const float* __restrict__ shift,
              unsigned short* __restrict__ C) {
    __shared__ unsigned short AL[64 * 104];
    int tid = (int)threadIdx.x, wv = tid >> 6, lane = tid & 63;
    int nb = (int)blockIdx.x * 64;
    int chunk = lane % 12;
    int eslot = lane / 12;
    int active = (lane < 48) ? 1 : 0;

    for (int t = 0; t < 16; t++) {
        int node = nb + wv * 16 + t;
        if (node >= GN) break;
        float di = dinv[node];
        int off = offs[node], cnt = indeg[node];
        float acc[8];
#pragma unroll
        for (int j = 0; j < 8; j++) acc[j] = 0.f;

        if (active) {
            for (int base = 0; base < cnt; base += 16) {
                int ss[4]; float ww[4]; bf16x8 hh[4];
#pragma unroll
                for (int k = 0; k < 4; k++) {
                    int e = base + k * 4 + eslot;
                    int s = node; float w = 0.f;
                    if (e < cnt) {
                        s = csr[off + e];
                        if ((unsigned)s >= (unsigned)GN) s = node;
                        w = dinv[s] * di;
                    }
                    ss[k] = s; ww[k] = w;
                }
#pragma unroll
                for (int k = 0; k < 4; k++)
                    hh[k] = *((const bf16x8*)(H + (size_t)ss[k] * 96 + chunk * 8));
#pragma unroll
                for (int k = 0; k < 4; k++)
#pragma unroll
                    for (int j = 0; j < 8; j++)
                        acc[j] += ww[k] * ar1_b2f((unsigned short)hh[k][j]);
            }
        }

        // writer lane c sums lanes {c, c+12, c+24, c+36}
#pragma unroll
        for (int j = 0; j < 8; j++) {
            float a1 = __shfl(acc[j], lane + 12, 64);
            float a2 = __shfl(acc[j], lane + 24, 64);
            float a3 = __shfl(acc[j], lane + 36, 64);
            acc[j] += a1 + a2 + a3;
        }

        if (lane < 12) {
            bf16x8 hs = *((const bf16x8*)(H + (size_t)node * 96 + chunk * 8));
            bf16x8 o;
#pragma unroll
            for (int j = 0; j < 8; j++)
                o[j] = (short)ar1_f2b(acc[j] + di * di * ar1_b2f((unsigned short)hs[j]));
            *((bf16x8*)(AL + (size_t)(wv * 16 + t) * 104 + chunk * 8)) = o;
        }
    }

    // phase 2: MFMA from wave-private LDS rows
    int m = lane & 15, quad = lane >> 4;
    floatx4 acc[6];
#pragma unroll
    for (int t = 0; t < 6; t++) acc[t] = (floatx4){0.f, 0.f, 0.f, 0.f};
#pragma unroll
    for (int c = 0; c < 3; c++) {
        bf16x8 a = *((const bf16x8*)(AL + (size_t)(wv * 16 + m) * 104 + c * 32 + quad * 8));
#pragma unroll
        for (int t = 0; t < 6; t++) {
            bf16x8 b = *((const bf16x8*)(Bp + ((size_t)(t * 3 + c) * 64 + lane) * 8));
            acc[t] = __builtin_amdgcn_mfma_f32_16x16x32_bf16(a, b, acc[t], 0, 0, 0);
        }
    }
#pragma unroll
    for (int t = 0; t < 6; t++) {
#pragma unroll
        for (int r = 0; r < 4; r++) {
            int row = nb + wv * 16 + quad * 4 + r;
            int col = t * 16 + m;
            if (row < GN) {
                float v = acc[t][r] * scale[col] + shift[col];
                C[(size_t)row * 96 + col] = ar1_f2b(fmaxf(v, 0.f));
            }
        }
    }
}

// ---------------- fused MLP: 96->256->128->64->8, one kernel ---------------
__global__ __launch_bounds__(256, 2)
void ar1_mlp(const unsigned short* __restrict__ A,
             const unsigned short* __restrict__ b3,
             const unsigned short* __restrict__ b4,
             const unsigned short* __restrict__ b5,
             const unsigned short* __restrict__ b6,
             const float* __restrict__ lb0, const float* __restrict__ lb1,
             const float* __restrict__ lb2, const float* __restrict__ lb3,
             void* __restrict__ out, const int* __restrict__ f32out) {
    __shared__ unsigned short H1[64 * 264];   // 256 cols
    __shared__ unsigned short H2[64 * 136];   // 128 cols
    __shared__ unsigned short H3[64 * 72];    // 64 cols
    int tid = (int)threadIdx.x, wv = tid >> 6, lane = tid & 63;
    int m = lane & 15, quad = lane >> 4;
    int mb = (int)blockIdx.x * 64 + wv * 16;
    int lwv = wv * 16;

    // ---- layer 1: 96 -> 256 (nch=3, NT=16) ----
    {
        int arow = mb + m; if (arow >= GN) arow = GN - 1;
        const unsigned short* Ap = A + (size_t)arow * 96 + quad * 8;
        floatx4 acc[16];
#pragma unroll
        for (int t = 0; t < 16; t++) acc[t] = (floatx4){0.f, 0.f, 0.f, 0.f};
        for (int c = 0; c < 3; c++) {
            bf16x8 a = *((const bf16x8*)(Ap + c * 32));
#pragma unroll
            for (int t = 0; t < 16; t++) {
                bf16x8 b = *((const bf16x8*)(b3 + ((size_t)(t * 3 + c) * 64 + lane) * 8));
                acc[t] = __builtin_amdgcn_mfma_f32_16x16x32_bf16(a, b, acc[t], 0, 0, 0);
            }
        }
#pragma unroll
        for (int t = 0; t < 16; t++)
#pragma unroll
            for (int r = 0; r < 4; r++) {
                int lr = lwv + quad * 4 + r, col = t * 16 + m;
                H1[lr * 264 + col] = ar1_f2b(fmaxf(acc[t][r] + lb0[col], 0.f));
            }
    }
    // ---- layer 2: 256 -> 128 (nch=8, NT=8) ----
    {
        const unsigned short* Hp = H1 + (size_t)(lwv + m) * 264 + quad * 8;
        floatx4 acc[8];
#pragma unroll
        for (int t = 0; t < 8; t++) acc[t] = (floatx4){0.f, 0.f, 0.f, 0.f};
        for (int c = 0; c < 8; c++) {
            bf16x8 a = *((const bf16x8*)(Hp + c * 32));
#pragma unroll
            for (int t = 0; t < 8; t++) {
                bf16x8 b = *((const bf16x8*)(b4 + ((size_t)(t * 8 + c) * 64 + lane) * 8));
                acc[t] = __builtin_amdgcn_mfma_f32_16x16x32_bf16(a, b, acc[t], 0, 0, 0);
            }
        }
#pragma unroll
        for (int t = 0; t < 8; t++)
#pragma unroll
            for (int r = 0; r < 4; r++) {
                int lr = lwv + quad * 4 + r, col = t * 16 + m;
                H2[lr * 136 + col] = ar1_f2b(fmaxf(acc[t][r] + lb1[col], 0.f));
            }
    }
    // ---- layer 3: 128 -> 64 (nch=4, NT=4) ----
    {
        const unsigned short* Hp = H2 + (size_t)(lwv + m) * 136 + quad * 8;
        floatx4 acc[4];
#pragma unroll
        for (int t = 0; t < 4; t++) acc[t] = (floatx4){0.f, 0.f, 0.f, 0.f};
        for (int c = 0; c < 4; c++) {
            bf16x8 a = *((const bf16x8*)(Hp + c * 32));
#pragma unroll
            for (int t = 0; t < 4; t++) {
                bf16x8 b = *((const bf16x8*)(b5 + ((size_t)(t * 4 + c) * 64 + lane) * 8));
                acc[t] = __builtin_amdgcn_mfma_f32_16x16x32_bf16(a, b, acc[t], 0, 0, 0);
            }
        }
#pragma unroll
        for (int t = 0; t < 4; t++)
#pragma unroll
            for (int r = 0; r < 4; r++) {
                int lr = lwv + quad * 4 + r, col = t * 16 + m;
                H3[lr * 72 + col] = ar1_f2b(fmaxf(acc[t][r] + lb2[col], 0.f));
            }
    }
    // ---- layer 4: 64 -> 8 (nch=2, NT=1, M padded 16) ----
    {
        const unsigned short* Hp = H3 + (size_t)(lwv + m) * 72 + quad * 8;
        floatx4 acc = (floatx4){0.f, 0.f, 0.f, 0.f};
        for (int c = 0; c < 2; c++) {
            bf16x8 a = *((const bf16x8*)(Hp + c * 32));
            bf16x8 b = *((const bf16x8*)(b6 + ((size_t)c * 64 + lane) * 8));
            acc = __builtin_amdgcn_mfma_f32_16x16x32_bf16(a, b, acc, 0, 0, 0);
        }
        int wf32 = f32out[0];
#pragma unroll
        for (int r = 0; r < 4; r++) {
            int row = mb + quad * 4 + r;
            if (row < GN && m < 8) {
                float v = acc[r] + lb3[m];
                if (wf32) ((float*)out)[(size_t)row * 8 + m] = v;
                else ((unsigned short*)out)[(size_t)row * 8 + m] = ar1_f2b(v);
            }
        }
    }
}

extern "C" void kernel_launch(void* const* d_in, const int* in_sizes, int n_in,
                              void* d_out, int out_size, void* d_ws, size_t ws_size,
                              hipStream_t stream) {
    (void)in_sizes; (void)n_in; (void)out_size;

    // workspace layout
    char* p = (char*)d_ws;
    unsigned short* bufA = (unsigned short*)p; p += (size_t)GN * 96 * 2;   // 9.6 MB
    unsigned short* bufC = (unsigned short*)p; p += (size_t)GN * 96 * 2;   // 9.6 MB
    unsigned int* pairs = (unsigned int*)p; p += (size_t)NPART * PSLOT * 4; // 3.6 MB
    int* indeg  = (int*)p;    p += (size_t)GN * 4;
    int* offs   = (int*)p;    p += (size_t)GN * 4;
    float* dinv = (float*)p;  p += (size_t)GN * 4;
    int* csr    = (int*)p;    p += (size_t)GE * 4;
    int* gcur   = (int*)p;    p += 1024;
    int* pbase  = (int*)p;    p += 1024;
    int* flagI  = (int*)p;    p += 1024;
    int* flagF  = (int*)p;    p += 1024;
    unsigned short* bpArena = (unsigned short*)p; p += 91136 * 2;  // packed W
    float* fArena = (float*)p; p += 2048 * 4;                      // small fp32
    size_t need = (size_t)(p - (char*)d_ws);
    if (ws_size < need) {
        hipMemsetAsync(d_out, 0x41, (size_t)GN * 8 * 2, stream);  // marker 12.06
        return;
    }

    // packed-weight arena offsets (shorts): w1,w2,w3,lw1,lw2,lw3,lw4
    unsigned short* bp[7];
    int bpn[7] = {6144, 9216, 9216, 24576, 32768, 8192, 1024};
    {
        unsigned short* q = bpArena;
        for (int i = 0; i < 7; i++) { bp[i] = q; q += bpn[i]; }
    }

    // small fp32 arena: lb1(256),lb2(128),lb3(64),lb4(8), 6 x 96 scale/shift
    float* lb[4]; float* ss[6];
    {
        float* q = fArena;
        int ln[4] = {256, 128, 64, 8};
        for (int i = 0; i < 4; i++) { lb[i] = q; q += ln[i]; }
        for (int i = 0; i < 6; i++) { ss[i] = q; q += 96; }
    }

    const int* ei = (const int*)d_in[1];

    // graph build (partition sort)
    ar1_detect<<<2, 256, 0, stream>>>(ei, (const unsigned short*)d_in[0], flagI, flagF, gcur);
    ar1_part<<<(GE + CHK - 1) / CHK, 256, 0, stream>>>(ei, flagI, gcur, pairs, GE);
    ar1_pscan<<<1, 128, 0, stream>>>(gcur, pbase);
    ar1_csr<<<NPART, 256, 0, stream>>>(pairs, gcur, pbase, csr, indeg, offs, dinv);

    // fused weight prep (pack 178 frags + small cvt/fold)
    {
        PackAll pa;
        int wsrc[7] = {2, 6, 10, 14, 16, 18, 20};
        int Ks[7] = {64, 96, 96, 96, 256, 128, 64};
        int Ms[7] = {96, 96, 96, 256, 128, 64, 8};
        int cum = 0;
        for (int i = 0; i < 7; i++) {
            pa.src[i] = d_in[wsrc[i]]; pa.dst[i] = bp[i];
            pa.K[i] = Ks[i]; pa.M[i] = Ms[i];
            pa.start[i] = cum;
            cum += (Ms[i] + 15) / 16 * (Ks[i] / 32);
        }
        pa.start[7] = cum;   // 178
        SmallCvt sc;
        int lsrc[4] = {15, 17, 19, 21};
        int ln[4] = {256, 128, 64, 8};
        for (int i = 0; i < 4; i++) { sc.src[i] = d_in[lsrc[i]]; sc.dst[i] = lb[i]; sc.n[i] = ln[i]; }
        int gsrc[9] = {3, 4, 5, 7, 8, 9, 11, 12, 13};
        for (int i = 0; i < 9; i++) sc.gb[i] = d_in[gsrc[i]];
        for (int i = 0; i < 6; i++) sc.ss[i] = ss[i];
        Arthur1_16458314678864_kernel<<<46, 256, 0, stream>>>(pa, sc, flagF);
    }

    const int FB = (GN + 63) / 64;    // fused layer blocks (64 nodes each)

    // GCN 1..3: fused aggregate+GEMM per layer
    ar1_ag64<<<FB, 256, 0, stream>>>(d_in[0], offs, indeg, csr, dinv, flagF,
                                     bp[0], ss[0], ss[1], bufA);
    ar1_ag96<<<FB, 256, 0, stream>>>(bufA, offs, indeg, csr, dinv,
                                     bp[1], ss[2], ss[3], bufC);
    ar1_ag96<<<FB, 256, 0, stream>>>(bufC, offs, indeg, csr, dinv,
                                     bp[2], ss[4], ss[5], bufA);

    // fused MLP: 96->256->128->64->8, writes d_out (fp32/bf16 per flagF)
    ar1_mlp<<<FB, 256, 0, stream>>>(bufA, bp[3], bp[4], bp[5], bp[6],
                                    lb[0], lb[1], lb[2], lb[3], d_out, flagF);
}

// Round 19
// 312.599 us; speedup vs baseline: 1.3288x; 1.3288x over previous
//
#include <hip/hip_runtime.h>

// GCN(3 layers) + MLP(4 layers), N=50000, E=800000, out = N x 8 bf16.
// NOTE: do NOT include <hip/hip_bf16.h> — breaks this harness's build
// (rounds 1-4 fell back to a stub; round 5 proved it). Manual bf16 ushort ops.
// Dtype runtime-detection: flagI (edge_index int64 vs int32), flagF (floats
// fp32 vs packed bf16).
//
// R19: revert R18's agg+gemm fusion (it cut gather TLP 16x: 50000 waves ->
// 3128, occupancy 62->28%, agg 42->93us — latency-bound gathers live on
// wave count; never fuse them into a compute-shaped grid). Restore R17's
// separate agg kernels (one node per wave, 12500 blocks). Apply fusion only
// compute->compute: GEMM3 (96->96 affine+ReLU) prepended to the MLP kernel
// (same 782-block row-local grid), LDS for its output aliasing the dead
// H2/H3 region (static LDS stays 60.4 KB). Saves one dispatch + 19.2 MB
// bufA round trip. Partition-sort CSR kept.

#define GN 50000
#define GE 800000
#define NPART 98        // partitions of 512 dst nodes
#define PSLOT 9216      // slab capacity per partition (mean 8163, +11 sigma)
#define CHK 2048        // edges per block in pass 1

typedef __attribute__((ext_vector_type(8))) short bf16x8;
typedef __attribute__((ext_vector_type(4))) float floatx4;

__device__ __forceinline__ float ar1_b2f(unsigned short h) {
    return __uint_as_float(((unsigned)h) << 16);
}
__device__ __forceinline__ unsigned short ar1_f2b(float f) {
    unsigned u = __float_as_uint(f);
    u = u + 0x7FFFu + ((u >> 16) & 1u);   // round-to-nearest-even
    return (unsigned short)(u >> 16);
}

// block 0: flagI (edge_index int64 <=> odd words ~all zero) + zero gcur
// block 1: flagF (floats fp32 vs packed bf16; see R6 notes)
__global__ void ar1_detect(const int* ei, const unsigned short* xw,
                           int* flagI, int* flagF, int* gcur) {
    __shared__ int cnt;
    if (threadIdx.x == 0) cnt = 0;
    __syncthreads();
    if (blockIdx.x == 0) {
        if ((int)threadIdx.x < NPART) gcur[threadIdx.x] = 0;
        if (ei[2 * threadIdx.x + 1] != 0) atomicAdd(&cnt, 1);
        __syncthreads();
        if (threadIdx.x == 0) flagI[0] = (cnt < 8) ? 1 : 0;
    } else {
        unsigned short w = xw[2 * threadIdx.x];
        int ex = (w >> 7) & 0xFF;
        if (w == 0 || (ex >= 90 && ex <= 150)) atomicAdd(&cnt, 1);
        __syncthreads();
        if (threadIdx.x == 0) flagF[0] = (cnt > 200) ? 0 : 1;
    }
}

// pass 1: partition edges into 98 slabs; packed word = s | (d&511)<<17
__global__ __launch_bounds__(256)
void ar1_part(const int* __restrict__ ei, const int* __restrict__ flagI,
              int* __restrict__ gcur, unsigned int* __restrict__ pairs, int E) {
    __shared__ int cnt[NPART], base[NPART], cur[NPART];
    int tid = (int)threadIdx.x;
    for (int i = tid; i < NPART; i += 256) { cnt[i] = 0; cur[i] = 0; }
    __syncthreads();
    int is64 = flagI[0];
    int e0 = (int)blockIdx.x * CHK;
    unsigned pk[8]; int q[8];
#pragma unroll
    for (int k = 0; k < 8; k++) {
        int e = e0 + k * 256 + tid;
        q[k] = -1; pk[k] = 0;
        if (e < E) {
            int s = is64 ? ei[2 * e] : ei[e];
            int d = is64 ? ei[2 * (E + e)] : ei[E + e];
            if ((unsigned)s < (unsigned)GN && (unsigned)d < (unsigned)GN) {
                int qq = d >> 9;
                q[k] = qq;
                pk[k] = (unsigned)s | ((unsigned)(d & 511) << 17);
                atomicAdd(&cnt[qq], 1);
            }
        }
    }
    __syncthreads();
    for (int i = tid; i < NPART; i += 256)
        base[i] = (cnt[i] > 0) ? atomicAdd(&gcur[i], cnt[i]) : 0;
    __syncthreads();
#pragma unroll
    for (int k = 0; k < 8; k++) {
        if (q[k] >= 0) {
            int r = base[q[k]] + atomicAdd(&cur[q[k]], 1);
            if (r < PSLOT) pairs[(size_t)q[k] * PSLOT + r] = pk[k];
        }
    }
}

// exclusive scan of partition sizes -> global CSR base per partition
__global__ void ar1_pscan(const int* gcur, int* pbase) {
    __shared__ int sm[128];
    int tid = (int)threadIdx.x;   // 128
    int v = (tid < NPART) ? gcur[tid] : 0;
    sm[tid] = v;
    __syncthreads();
    for (int off = 1; off < 128; off <<= 1) {
        int t = (tid >= off) ? sm[tid - off] : 0;
        __syncthreads();
        sm[tid] += t;
        __syncthreads();
    }
    if (tid < NPART) pbase[tid] = sm[tid] - v;
}

// pass 2: per-partition -> contiguous CSR slice + indeg/offs/dinv
__global__ __launch_bounds__(256)
void ar1_csr(const unsigned int* __restrict__ pairs, const int* __restrict__ gcur,
             const int* __restrict__ pbase, int* __restrict__ csr,
             int* __restrict__ indeg, int* __restrict__ offs,
             float* __restrict__ dinv) {
    __shared__ int ncnt[512], pre[512], cur[512], psum[16];
    int p = (int)blockIdx.x, tid = (int)threadIdx.x;
    int cntE = gcur[p];
    if (cntE > PSLOT) cntE = PSLOT;
    int gbase = pbase[p];
    for (int i = tid; i < 512; i += 256) ncnt[i] = 0;
    __syncthreads();
    const unsigned int* pp = pairs + (size_t)p * PSLOT;
    for (int i = tid; i < cntE; i += 256) atomicAdd(&ncnt[pp[i] >> 17], 1);
    __syncthreads();
    if (tid < 16) {
        int s = 0;
        for (int j = tid * 32; j < tid * 32 + 32; j++) { pre[j] = s; s += ncnt[j]; }
        psum[tid] = s;
    }
    __syncthreads();
    if (tid == 0) {
        int s = 0;
        for (int j = 0; j < 16; j++) { int t = psum[j]; psum[j] = s; s += t; }
    }
    __syncthreads();
    if (tid < 16)
        for (int j = tid * 32; j < tid * 32 + 32; j++) pre[j] += psum[tid];
    __syncthreads();
    for (int j = tid; j < 512; j += 256) {
        cur[j] = pre[j];
        int node = p * 512 + j;
        if (node < GN) {
            indeg[node] = ncnt[j];
            offs[node] = gbase + pre[j];
            dinv[node] = rsqrtf((float)(ncnt[j] + 1));   // +1: self loop
        }
    }
    __syncthreads();
    for (int i = tid; i < cntE; i += 256) {
        unsigned v = pp[i];
        int r = atomicAdd(&cur[v >> 17], 1);
        csr[gbase + r] = (int)(v & 0x1FFFFu);
    }
}

struct PackAll {
    const void* src[7];
    unsigned short* dst[7];
    int K[7], M[7], start[8];
};
struct SmallCvt {
    const void* src[4];   // lb1, lb2, lb3, lb4
    float* dst[4];
    int n[4];
    const void* gb[9];    // b1,g1,be1, b2,g2,be2, b3,g3,be3
    float* ss[6];         // scale1,shift1, ...
};

// fused weight prep (carries the harness kernel name):
// blocks 0..44: pack 4 fragments each into MFMA B order (178 frags total);
// block 45: small-vector cvt + GCN bias/BN fold (scale=C*g, shift=b*C*g+be).
__global__ void Arthur1_16458314678864_kernel(PackAll pa, SmallCvt sc,
                                              const int* flagF) {
    int b = (int)blockIdx.x;
    int f = flagF[0];
    if (b < 45) {
        int frag_g = b * 4 + ((int)threadIdx.x >> 6);
        if (frag_g >= 178) return;
        int w = 0;
        while (w < 6 && frag_g >= pa.start[w + 1]) w++;
        int frag = frag_g - pa.start[w];
        int K = pa.K[w], M = pa.M[w];
        int lane = (int)threadIdx.x & 63;
        int nch = K >> 5;
        int t = frag / nch, c = frag - t * nch;
        int n = t * 16 + (lane & 15);
        int k0 = c * 32 + (lane >> 4) * 8;
        unsigned short* o = pa.dst[w] + ((size_t)frag * 64 + lane) * 8;
        for (int j = 0; j < 8; j++) {
            unsigned short v = 0;
            if (n < M) {
                int idx = (k0 + j) * M + n;
                v = f ? ar1_f2b(((const float*)pa.src[w])[idx])
                      : ((const unsigned short*)pa.src[w])[idx];
            }
            o[j] = v;
        }
    } else {
        const float C = 0.9999950000374997f;   // 1/sqrt(1+1e-5)
        for (int s = 0; s < 4; s++) {
            for (int i = threadIdx.x; i < sc.n[s]; i += 256) {
                float v = f ? ((const float*)sc.src[s])[i]
                            : ar1_b2f(((const unsigned short*)sc.src[s])[i]);
                sc.dst[s][i] = v;
            }
        }
        for (int k = 0; k < 3; k++) {
            for (int i = threadIdx.x; i < 96; i += 256) {
                float bb, g, be;
                if (f) {
                    bb = ((const float*)sc.gb[3 * k + 0])[i];
                    g  = ((const float*)sc.gb[3 * k + 1])[i];
                    be = ((const float*)sc.gb[3 * k + 2])[i];
                } else {
                    bb = ar1_b2f(((const unsigned short*)sc.gb[3 * k + 0])[i]);
                    g  = ar1_b2f(((const unsigned short*)sc.gb[3 * k + 1])[i]);
                    be = ar1_b2f(((const unsigned short*)sc.gb[3 * k + 2])[i]);
                }
                sc.ss[2 * k + 0][i] = C * g;
                sc.ss[2 * k + 1][i] = bb * C * g + be;
            }
        }
    }
}

// ---------------- MFMA GEMM (GCN layers 1,2): C = A@W, affine+ReLU ----------
template <int NT>
__global__ __launch_bounds__(256, 2)
void ar1_mfma(const unsigned short* __restrict__ A,
              const unsigned short* __restrict__ Bp,
              const float* __restrict__ scale, const float* __restrict__ shift,
              unsigned short* __restrict__ C, int K, int Astride, int Cstride) {
    int tid = (int)threadIdx.x;
    int wv = tid >> 6, lane = tid & 63;
    int mb = ((int)blockIdx.x * 4 + wv) * 16;
    int m = lane & 15, quad = lane >> 4;
    int arow = mb + m;
    if (arow >= GN) arow = GN - 1;          // clamp; rows >= GN never stored
    const unsigned short* Aptr = A + (size_t)arow * Astride + quad * 8;
    int nch = K >> 5;

    floatx4 acc[NT];
#pragma unroll
    for (int t = 0; t < NT; t++) acc[t] = (floatx4){0.f, 0.f, 0.f, 0.f};

    for (int c = 0; c < nch; c++) {
        bf16x8 a = *((const bf16x8*)(Aptr + c * 32));
#pragma unroll
        for (int t = 0; t < NT; t++) {
            bf16x8 b = *((const bf16x8*)(Bp + ((size_t)(t * nch + c) * 64 + lane) * 8));
            acc[t] = __builtin_amdgcn_mfma_f32_16x16x32_bf16(a, b, acc[t], 0, 0, 0);
        }
    }

#pragma unroll
    for (int t = 0; t < NT; t++) {
#pragma unroll
        for (int r = 0; r < 4; r++) {
            int row = mb + quad * 4 + r;
            int col = t * 16 + m;
            if (row < GN) {
                float v = acc[t][r] * scale[col] + shift[col];
                C[(size_t)row * Cstride + col] = ar1_f2b(fmaxf(v, 0.f));
            }
        }
    }
}

// ---------------- fused GEMM3 + MLP: 96->96 then 96->256->128->64->8 --------
// Stage 0 = GCN layer-3 GEMM (affine+ReLU) from global agg rows -> LDS H0;
// H0 aliases the H2/H3 region (dead until layer 2). Wave owns 16 rows
// end-to-end; all LDS slices wave-private (no barriers).
__global__ __launch_bounds__(256, 2)
void ar1_mlp2(const unsigned short* __restrict__ A,   // layer-3 agg, stride 96
              const unsigned short* __restrict__ b2w, // gemm3 weights (packed)
              const float* __restrict__ sc3, const float* __restrict__ sh3,
              const unsigned short* __restrict__ b3,
              const unsigned short* __restrict__ b4,
              const unsigned short* __restrict__ b5,
              const unsigned short* __restrict__ b6,
              const float* __restrict__ lb0, const float* __restrict__ lb1,
              const float* __restrict__ lb2, const float* __restrict__ lb3,
              void* __restrict__ out, const int* __restrict__ f32out) {
    __shared__ unsigned short SH[16896 + 13312];      // H1 | union(H0 / H2+H3)
    unsigned short* H1 = SH;                          // 64 x 264 (256 cols)
    unsigned short* H0 = SH + 16896;                  // 64 x 104 (96 cols)
    unsigned short* H2 = SH + 16896;                  // 64 x 136 (128 cols)
    unsigned short* H3 = SH + 16896 + 8704;           // 64 x 72  (64 cols)
    int tid = (int)threadIdx.x, wv = tid >> 6, lane = tid & 63;
    int m = lane & 15, quad = lane >> 4;
    int mb = (int)blockIdx.x * 64 + wv * 16;
    int lwv = wv * 16;

    // ---- stage 0: GCN layer-3 GEMM 96 -> 96 (nch=3, NT=6), affine+ReLU ----
    {
        int arow = mb + m; if (arow >= GN) arow = GN - 1;
        const unsigned short* Ap = A + (size_t)arow * 96 + quad * 8;
        floatx4 acc[6];
#pragma unroll
        for (int t = 0; t < 6; t++) acc[t] = (floatx4){0.f, 0.f, 0.f, 0.f};
        for (int c = 0; c < 3; c++) {
            bf16x8 a = *((const bf16x8*)(Ap + c * 32));
#pragma unroll
            for (int t = 0; t < 6; t++) {
                bf16x8 b = *((const bf16x8*)(b2w + ((size_t)(t * 3 + c) * 64 + lane) * 8));
                acc[t] = __builtin_amdgcn_mfma_f32_16x16x32_bf16(a, b, acc[t], 0, 0, 0);
            }
        }
#pragma unroll
        for (int t = 0; t < 6; t++)
#pragma unroll
            for (int r = 0; r < 4; r++) {
                int lr = lwv + quad * 4 + r, col = t * 16 + m;
                float v = acc[t][r] * sc3[col] + sh3[col];
                H0[lr * 104 + col] = ar1_f2b(fmaxf(v, 0.f));
            }
    }
    // ---- layer 1: 96 -> 256 (nch=3, NT=16), from H0 ----
    {
        const unsigned short* Hp = H0 + (size_t)(lwv + m) * 104 + quad * 8;
        floatx4 acc[16];
#pragma unroll
        for (int t = 0; t < 16; t++) acc[t] = (floatx4){0.f, 0.f, 0.f, 0.f};
        for (int c = 0; c < 3; c++) {
            bf16x8 a = *((const bf16x8*)(Hp + c * 32));
#pragma unroll
            for (int t = 0; t < 16; t++) {
                bf16x8 b = *((const bf16x8*)(b3 + ((size_t)(t * 3 + c) * 64 + lane) * 8));
                acc[t] = __builtin_amdgcn_mfma_f32_16x16x32_bf16(a, b, acc[t], 0, 0, 0);
            }
        }
#pragma unroll
        for (int t = 0; t < 16; t++)
#pragma unroll
            for (int r = 0; r < 4; r++) {
                int lr = lwv + quad * 4 + r, col = t * 16 + m;
                H1[lr * 264 + col] = ar1_f2b(fmaxf(acc[t][r] + lb0[col], 0.f));
            }
    }
    // ---- layer 2: 256 -> 128 (nch=8, NT=8) ----  (H0 dead; H2 overwrites it)
    {
        const unsigned short* Hp = H1 + (size_t)(lwv + m) * 264 + quad * 8;
        floatx4 acc[8];
#pragma unroll
        for (int t = 0; t < 8; t++) acc[t] = (floatx4){0.f, 0.f, 0.f, 0.f};
        for (int c = 0; c < 8; c++) {
            bf16x8 a = *((const bf16x8*)(Hp + c * 32));
#pragma unroll
            for (int t = 0; t < 8; t++) {
                bf16x8 b = *((const bf16x8*)(b4 + ((size_t)(t * 8 + c) * 64 + lane) * 8));
                acc[t] = __builtin_amdgcn_mfma_f32_16x16x32_bf16(a, b, acc[t], 0, 0, 0);
            }
        }
#pragma unroll
        for (int t = 0; t < 8; t++)
#pragma unroll
            for (int r = 0; r < 4; r++) {
                int lr = lwv + quad * 4 + r, col = t * 16 + m;
                H2[lr * 136 + col] = ar1_f2b(fmaxf(acc[t][r] + lb1[col], 0.f));
            }
    }
    // ---- layer 3: 128 -> 64 (nch=4, NT=4) ----
    {
        const unsigned short* Hp = H2 + (size_t)(lwv + m) * 136 + quad * 8;
        floatx4 acc[4];
#pragma unroll
        for (int t = 0; t < 4; t++) acc[t] = (floatx4){0.f, 0.f, 0.f, 0.f};
        for (int c = 0; c < 4; c++) {
            bf16x8 a = *((const bf16x8*)(Hp + c * 32));
#pragma unroll
            for (int t = 0; t < 4; t++) {
                bf16x8 b = *((const bf16x8*)(b5 + ((size_t)(t * 4 + c) * 64 + lane) * 8));
                acc[t] = __builtin_amdgcn_mfma_f32_16x16x32_bf16(a, b, acc[t], 0, 0, 0);
            }
        }
#pragma unroll
        for (int t = 0; t < 4; t++)
#pragma unroll
            for (int r = 0; r < 4; r++) {
                int lr = lwv + quad * 4 + r, col = t * 16 + m;
                H3[lr * 72 + col] = ar1_f2b(fmaxf(acc[t][r] + lb2[col], 0.f));
            }
    }
    // ---- layer 4: 64 -> 8 (nch=2, NT=1, M padded 16) ----
    {
        const unsigned short* Hp = H3 + (size_t)(lwv + m) * 72 + quad * 8;
        floatx4 acc = (floatx4){0.f, 0.f, 0.f, 0.f};
        for (int c = 0; c < 2; c++) {
            bf16x8 a = *((const bf16x8*)(Hp + c * 32));
            bf16x8 b = *((const bf16x8*)(b6 + ((size_t)c * 64 + lane) * 8));
            acc = __builtin_amdgcn_mfma_f32_16x16x32_bf16(a, b, acc, 0, 0, 0);
        }
        int wf32 = f32out[0];
#pragma unroll
        for (int r = 0; r < 4; r++) {
            int row = mb + quad * 4 + r;
            if (row < GN && m < 8) {
                float v = acc[r] + lb3[m];
                if (wf32) ((float*)out)[(size_t)row * 8 + m] = v;
                else ((unsigned short*)out)[(size_t)row * 8 + m] = ar1_f2b(v);
            }
        }
    }
}

// ---------------- aggregate over x (64-dim), reading d_in[0] directly ------
// lane = eslot(3b) x chunk(3b); 2x unroll; one node per wave.
__global__ __launch_bounds__(256, 8)
void ar1_agg64(const void* __restrict__ Xv, const int* __restrict__ offs,
               const int* __restrict__ indeg, const int* __restrict__ csr,
               const float* __restrict__ dinv, const int* __restrict__ flagF,
               unsigned short* __restrict__ Out) {
    int wv = (int)threadIdx.x >> 6, lane = (int)threadIdx.x & 63;
    int node = (int)blockIdx.x * 4 + wv;
    if (node >= GN) return;
    int chunk = lane & 7;      // feats chunk*8 .. +8
    int eslot = lane >> 3;     // 0..7
    float di = dinv[node];
    int off = offs[node], cnt = indeg[node];
    int f = flagF[0];
    const unsigned short* X16 = (const unsigned short*)Xv;
    const float* X32 = (const float*)Xv;

    float acc[8];
#pragma unroll
    for (int j = 0; j < 8; j++) acc[j] = 0.f;

    for (int base = 0; base < cnt; base += 16) {
        int ss[2]; float ww[2];
#pragma unroll
        for (int k = 0; k < 2; k++) {
            int e = base + k * 8 + eslot;
            int s = node; float w = 0.f;
            if (e < cnt) {
                s = csr[off + e];
                if ((unsigned)s >= (unsigned)GN) s = node;
                w = dinv[s] * di;
            }
            ss[k] = s; ww[k] = w;
        }
#pragma unroll
        for (int k = 0; k < 2; k++) {
            float hv[8];
            if (f) {
                floatx4 a = *((const floatx4*)(X32 + (size_t)ss[k] * 64 + chunk * 8));
                floatx4 b = *((const floatx4*)(X32 + (size_t)ss[k] * 64 + chunk * 8 + 4));
#pragma unroll
                for (int j = 0; j < 4; j++) { hv[j] = a[j]; hv[4 + j] = b[j]; }
            } else {
                bf16x8 h = *((const bf16x8*)(X16 + (size_t)ss[k] * 64 + chunk * 8));
#pragma unroll
                for (int j = 0; j < 8; j++) hv[j] = ar1_b2f((unsigned short)h[j]);
            }
#pragma unroll
            for (int j = 0; j < 8; j++) acc[j] += ww[k] * hv[j];
        }
    }

#pragma unroll
    for (int j = 0; j < 8; j++) {
        acc[j] += __shfl_xor(acc[j], 8, 64);
        acc[j] += __shfl_xor(acc[j], 16, 64);
        acc[j] += __shfl_xor(acc[j], 32, 64);
    }

    if (eslot == 0) {
        float hv[8];
        if (f) {
            floatx4 a = *((const floatx4*)(X32 + (size_t)node * 64 + chunk * 8));
            floatx4 b = *((const floatx4*)(X32 + (size_t)node * 64 + chunk * 8 + 4));
#pragma unroll
            for (int j = 0; j < 4; j++) { hv[j] = a[j]; hv[4 + j] = b[j]; }
        } else {
            bf16x8 h = *((const bf16x8*)(X16 + (size_t)node * 64 + chunk * 8));
#pragma unroll
            for (int j = 0; j < 8; j++) hv[j] = ar1_b2f((unsigned short)h[j]);
        }
#pragma unroll
        for (int j = 0; j < 8; j++) {
            float v = acc[j] + di * di * hv[j];
            Out[(size_t)node * 64 + chunk * 8 + j] = ar1_f2b(v);
        }
    }
}

// ---------------- aggregate, 96-dim rows, stride 96 (layers 2,3) ------------
// 192 B rows = 3 lines, 64B-aligned. 4 eslots x 12 chunks; 4x edge unroll;
// one node per wave; dynamic-shfl reduce; self-loop fused.
__global__ __launch_bounds__(256, 8)
void ar1_agg96(const unsigned short* __restrict__ H, const int* __restrict__ offs,
               const int* __restrict__ indeg, const int* __restrict__ csr,
               const float* __restrict__ dinv, unsigned short* __restrict__ Out) {
    int wv = (int)threadIdx.x >> 6, lane = (int)threadIdx.x & 63;
    int node = (int)blockIdx.x * 4 + wv;
    if (node >= GN) return;
    int chunk = lane % 12;     // feats chunk*8 .. +8
    int eslot = lane / 12;     // 0..3 active
    int active = (lane < 48) ? 1 : 0;
    float di = dinv[node];
    int off = offs[node], cnt = indeg[node];

    float acc[8];
#pragma unroll
    for (int j = 0; j < 8; j++) acc[j] = 0.f;

    if (active) {
        for (int base = 0; base < cnt; base += 16) {
            int ss[4]; float ww[4]; bf16x8 hh[4];
#pragma unroll
            for (int k = 0; k < 4; k++) {
                int e = base + k * 4 + eslot;
                int s = node; float w = 0.f;
                if (e < cnt) {
                    s = csr[off + e];
                    if ((unsigned)s >= (unsigned)GN) s = node;
                    w = dinv[s] * di;
                }
                ss[k] = s; ww[k] = w;
            }
#pragma unroll
            for (int k = 0; k < 4; k++)
                hh[k] = *((const bf16x8*)(H + (size_t)ss[k] * 96 + chunk * 8));
#pragma unroll
            for (int k = 0; k < 4; k++)
#pragma unroll
                for (int j = 0; j < 8; j++)
                    acc[j] += ww[k] * ar1_b2f((unsigned short)hh[k][j]);
        }
    }

    // writer lane c sums lanes {c, c+12, c+24, c+36}
#pragma unroll
    for (int j = 0; j < 8; j++) {
        float a1 = __shfl(acc[j], lane + 12, 64);
        float a2 = __shfl(acc[j], lane + 24, 64);
        float a3 = __shfl(acc[j], lane + 36, 64);
        acc[j] += a1 + a2 + a3;
    }

    if (lane < 12) {
        bf16x8 hs = *((const bf16x8*)(H + (size_t)node * 96 + chunk * 8));
#pragma unroll
        for (int j = 0; j < 8; j++) {
            float v = acc[j] + di * di * ar1_b2f((unsigned short)hs[j]);
            Out[(size_t)node * 96 + chunk * 8 + j] = ar1_f2b(v);
        }
    }
}

extern "C" void kernel_launch(void* const* d_in, const int* in_sizes, int n_in,
                              void* d_out, int out_size, void* d_ws, size_t ws_size,
                              hipStream_t stream) {
    (void)in_sizes; (void)n_in; (void)out_size;

    // workspace layout
    char* p = (char*)d_ws;
    unsigned short* bufA = (unsigned short*)p; p += (size_t)GN * 96 * 2;   // 9.6 MB
    unsigned short* bufC = (unsigned short*)p; p += (size_t)GN * 96 * 2;   // 9.6 MB
    unsigned int* pairs = (unsigned int*)p; p += (size_t)NPART * PSLOT * 4; // 3.6 MB
    int* indeg  = (int*)p;    p += (size_t)GN * 4;
    int* offs   = (int*)p;    p += (size_t)GN * 4;
    float* dinv = (float*)p;  p += (size_t)GN * 4;
    int* csr    = (int*)p;    p += (size_t)GE * 4;
    int* gcur   = (int*)p;    p += 1024;
    int* pbase  = (int*)p;    p += 1024;
    int* flagI  = (int*)p;    p += 1024;
    int* flagF  = (int*)p;    p += 1024;
    unsigned short* bpArena = (unsigned short*)p; p += 91136 * 2;  // packed W
    float* fArena = (float*)p; p += 2048 * 4;                      // small fp32
    size_t need = (size_t)(p - (char*)d_ws);
    if (ws_size < need) {
        hipMemsetAsync(d_out, 0x41, (size_t)GN * 8 * 2, stream);  // marker 12.06
        return;
    }

    // packed-weight arena offsets (shorts): w1,w2,w3,lw1,lw2,lw3,lw4
    unsigned short* bp[7];
    int bpn[7] = {6144, 9216, 9216, 24576, 32768, 8192, 1024};
    {
        unsigned short* q = bpArena;
        for (int i = 0; i < 7; i++) { bp[i] = q; q += bpn[i]; }
    }

    // small fp32 arena: lb1(256),lb2(128),lb3(64),lb4(8), 6 x 96 scale/shift
    float* lb[4]; float* ss[6];
    {
        float* q = fArena;
        int ln[4] = {256, 128, 64, 8};
        for (int i = 0; i < 4; i++) { lb[i] = q; q += ln[i]; }
        for (int i = 0; i < 6; i++) { ss[i] = q; q += 96; }
    }

    const int* ei = (const int*)d_in[1];

    // graph build (partition sort)
    ar1_detect<<<2, 256, 0, stream>>>(ei, (const unsigned short*)d_in[0], flagI, flagF, gcur);
    ar1_part<<<(GE + CHK - 1) / CHK, 256, 0, stream>>>(ei, flagI, gcur, pairs, GE);
    ar1_pscan<<<1, 128, 0, stream>>>(gcur, pbase);
    ar1_csr<<<NPART, 256, 0, stream>>>(pairs, gcur, pbase, csr, indeg, offs, dinv);

    // fused weight prep (pack 178 frags + small cvt/fold)
    {
        PackAll pa;
        int wsrc[7] = {2, 6, 10, 14, 16, 18, 20};
        int Ks[7] = {64, 96, 96, 96, 256, 128, 64};
        int Ms[7] = {96, 96, 96, 256, 128, 64, 8};
        int cum = 0;
        for (int i = 0; i < 7; i++) {
            pa.src[i] = d_in[wsrc[i]]; pa.dst[i] = bp[i];
            pa.K[i] = Ks[i]; pa.M[i] = Ms[i];
            pa.start[i] = cum;
            cum += (Ms[i] + 15) / 16 * (Ks[i] / 32);
        }
        pa.start[7] = cum;   // 178
        SmallCvt sc;
        int lsrc[4] = {15, 17, 19, 21};
        int ln[4] = {256, 128, 64, 8};
        for (int i = 0; i < 4; i++) { sc.src[i] = d_in[lsrc[i]]; sc.dst[i] = lb[i]; sc.n[i] = ln[i]; }
        int gsrc[9] = {3, 4, 5, 7, 8, 9, 11, 12, 13};
        for (int i = 0; i < 9; i++) sc.gb[i] = d_in[gsrc[i]];
        for (int i = 0; i < 6; i++) sc.ss[i] = ss[i];
        Arthur1_16458314678864_kernel<<<46, 256, 0, stream>>>(pa, sc, flagF);
    }

    const int GB = (GN + 63) / 64;    // 64 rows per block
    const int AB = GN / 4;            // agg: 4 nodes per block (12500 exact)

    // GCN: agg (one node/wave, 50000 waves) then GEMM; layer-3 GEMM in MLP
    ar1_agg64<<<AB, 256, 0, stream>>>(d_in[0], offs, indeg, csr, dinv, flagF, bufC);
    ar1_mfma<6><<<GB, 256, 0, stream>>>(bufC, bp[0], ss[0], ss[1], bufA, 64, 64, 96);
    ar1_agg96<<<AB, 256, 0, stream>>>(bufA, offs, indeg, csr, dinv, bufC);
    ar1_mfma<6><<<GB, 256, 0, stream>>>(bufC, bp[1], ss[2], ss[3], bufA, 96, 96, 96);
    ar1_agg96<<<AB, 256, 0, stream>>>(bufA, offs, indeg, csr, dinv, bufC);

    // fused GEMM3 + MLP -> d_out (fp32/bf16 per flagF)
    ar1_mlp2<<<GB, 256, 0, stream>>>(bufC, bp[2], ss[4], ss[5],
                                     bp[3], bp[4], bp[5], bp[6],
                                     lb[0], lb[1], lb[2], lb[3], d_out, flagF);
}

// Round 20
// 292.778 us; speedup vs baseline: 1.4187x; 1.0677x over previous
//
#include <hip/hip_runtime.h>

// GCN(3 layers) + MLP(4 layers), N=50000, E=800000, out = N x 8 bf16.
// NOTE: do NOT include <hip/hip_bf16.h> — breaks this harness's build
// (rounds 1-4 fell back to a stub; round 5 proved it). Manual bf16 ushort ops.
// Dtype runtime-detection: flagI (edge_index int64 vs int32), flagF (floats
// fp32 vs packed bf16) — now self-detected per block via butterfly reduce.
//
// R20: (a) GEMM1/GEMM2 fused into the aggregates TLP-safely: 1024-thread
// blocks = 16 waves = 16 nodes, ONE NODE PER WAVE (50000 gather waves kept;
// R18's failure was 16 nodes/wave serially). One barrier, then waves 0..5
// each run one 16-col slice of the 16-row MFMA from LDS. Kills 2 dispatches
// + 32 MB round-trip. (b) graph prep: memset + merged part/pack/cvt kernel
// (blocks self-detect dtypes) + csr with self-scan: 5 dispatches -> 2+memset.
// Total 11 -> 7 dispatches. agg gather itself is at the random-access wall
// (FETCH = 8 XCD x H). Partition-sort CSR + fused GEMM3+MLP kept.

#define GN 50000
#define GE 800000
#define NPART 98        // partitions of 512 dst nodes
#define PSLOT 9216      // slab capacity per partition (mean 8163, +11 sigma)
#define CHK 2048        // edges per block in pass 1

typedef __attribute__((ext_vector_type(8))) short bf16x8;
typedef __attribute__((ext_vector_type(4))) float floatx4;

__device__ __forceinline__ float ar1_b2f(unsigned short h) {
    return __uint_as_float(((unsigned)h) << 16);
}
__device__ __forceinline__ unsigned short ar1_f2b(float f) {
    unsigned u = __float_as_uint(f);
    u = u + 0x7FFFu + ((u >> 16) & 1u);   // round-to-nearest-even
    return (unsigned short)(u >> 16);
}

// wave-parallel detectors (4 loads + butterfly; every wave gets the answer)
__device__ __forceinline__ int ar1_det64(const int* ei) {
    int l = (int)threadIdx.x & 63;
    int nz = 0;
#pragma unroll
    for (int k = 0; k < 4; k++)
        nz += (ei[2 * (l + 64 * k) + 1] != 0) ? 1 : 0;
#pragma unroll
    for (int o = 1; o < 64; o <<= 1)
        nz += __shfl_xor(nz, o, 64);
    return (nz < 8) ? 1 : 0;                 // 1 => int64
}
__device__ __forceinline__ int ar1_detf32(const unsigned short* xw) {
    int l = (int)threadIdx.x & 63;
    int c = 0;
#pragma unroll
    for (int k = 0; k < 4; k++) {
        unsigned short w = xw[2 * (l + 64 * k)];
        int ex = (w >> 7) & 0xFF;
        if (w == 0 || (ex >= 90 && ex <= 150)) c++;
    }
#pragma unroll
    for (int o = 1; o < 64; o <<= 1)
        c += __shfl_xor(c, o, 64);
    return (c > 200) ? 0 : 1;                // 1 => fp32
}

struct PackAll {
    const void* src[7];
    unsigned short* dst[7];
    int K[7], M[7], start[8];
};
struct SmallCvt {
    const void* src[4];   // lb1, lb2, lb3, lb4
    float* dst[4];
    int n[4];
    const void* gb[9];    // b1,g1,be1, b2,g2,be2, b3,g3,be3
    float* ss[6];         // scale1,shift1, ...
};

// merged prep (carries harness kernel name), grid = 391 + 45 + 1 = 437:
//  b<391: edge partition pass (self-detected is64); needs gcur pre-zeroed.
//  b<436: pack 4 MFMA B-fragments each (self-detected flagF).
//  b==436: small cvt + BN fold; writes flagI/flagF for downstream kernels.
__global__ __launch_bounds__(256)
void Arthur1_16458314678864_kernel(PackAll pa, SmallCvt sc,
                                   const int* __restrict__ ei,
                                   const unsigned short* __restrict__ xw,
                                   int* flagI, int* flagF,
                                   int* __restrict__ gcur,
                                   unsigned int* __restrict__ pairs) {
    int b = (int)blockIdx.x;
    int tid = (int)threadIdx.x;
    if (b < 391) {
        __shared__ int cnt[NPART], base[NPART], cur[NPART];
        for (int i = tid; i < NPART; i += 256) { cnt[i] = 0; cur[i] = 0; }
        int is64 = ar1_det64(ei);
        __syncthreads();
        int e0 = b * CHK;
        unsigned pk[8]; int q[8];
#pragma unroll
        for (int k = 0; k < 8; k++) {
            int e = e0 + k * 256 + tid;
            q[k] = -1; pk[k] = 0;
            if (e < GE) {
                int s = is64 ? ei[2 * e] : ei[e];
                int d = is64 ? ei[2 * (GE + e)] : ei[GE + e];
                if ((unsigned)s < (unsigned)GN && (unsigned)d < (unsigned)GN) {
                    int qq = d >> 9;
                    q[k] = qq;
                    pk[k] = (unsigned)s | ((unsigned)(d & 511) << 17);
                    atomicAdd(&cnt[qq], 1);
                }
            }
        }
        __syncthreads();
        for (int i = tid; i < NPART; i += 256)
            base[i] = (cnt[i] > 0) ? atomicAdd(&gcur[i], cnt[i]) : 0;
        __syncthreads();
#pragma unroll
        for (int k = 0; k < 8; k++) {
            if (q[k] >= 0) {
                int r = base[q[k]] + atomicAdd(&cur[q[k]], 1);
                if (r < PSLOT) pairs[(size_t)q[k] * PSLOT + r] = pk[k];
            }
        }
    } else if (b < 436) {
        int f = ar1_detf32(xw);
        int frag_g = (b - 391) * 4 + (tid >> 6);
        if (frag_g >= 178) return;
        int w = 0;
        while (w < 6 && frag_g >= pa.start[w + 1]) w++;
        int frag = frag_g - pa.start[w];
        int K = pa.K[w], M = pa.M[w];
        int lane = tid & 63;
        int nch = K >> 5;
        int t = frag / nch, c = frag - t * nch;
        int n = t * 16 + (lane & 15);
        int k0 = c * 32 + (lane >> 4) * 8;
        unsigned short* o = pa.dst[w] + ((size_t)frag * 64 + lane) * 8;
        for (int j = 0; j < 8; j++) {
            unsigned short v = 0;
            if (n < M) {
                int idx = (k0 + j) * M + n;
                v = f ? ar1_f2b(((const float*)pa.src[w])[idx])
                      : ((const unsigned short*)pa.src[w])[idx];
            }
            o[j] = v;
        }
    } else {
        int f = ar1_detf32(xw);
        int i64 = ar1_det64(ei);
        if (tid == 0) { flagI[0] = i64; flagF[0] = f; }
        const float C = 0.9999950000374997f;   // 1/sqrt(1+1e-5)
        for (int s = 0; s < 4; s++) {
            for (int i = tid; i < sc.n[s]; i += 256) {
                float v = f ? ((const float*)sc.src[s])[i]
                            : ar1_b2f(((const unsigned short*)sc.src[s])[i]);
                sc.dst[s][i] = v;
            }
        }
        for (int k = 0; k < 3; k++) {
            for (int i = tid; i < 96; i += 256) {
                float bb, g, be;
                if (f) {
                    bb = ((const float*)sc.gb[3 * k + 0])[i];
                    g  = ((const float*)sc.gb[3 * k + 1])[i];
                    be = ((const float*)sc.gb[3 * k + 2])[i];
                } else {
                    bb = ar1_b2f(((const unsigned short*)sc.gb[3 * k + 0])[i]);
                    g  = ar1_b2f(((const unsigned short*)sc.gb[3 * k + 1])[i]);
                    be = ar1_b2f(((const unsigned short*)sc.gb[3 * k + 2])[i]);
                }
                sc.ss[2 * k + 0][i] = C * g;
                sc.ss[2 * k + 1][i] = bb * C * g + be;
            }
        }
    }
}

// per-partition -> contiguous CSR slice + indeg/offs/dinv (self-scans gbase)
__global__ __launch_bounds__(256)
void ar1_csr(const unsigned int* __restrict__ pairs, const int* __restrict__ gcur,
             int* __restrict__ csr, int* __restrict__ indeg,
             int* __restrict__ offs, float* __restrict__ dinv) {
    __shared__ int ncnt[512], pre[512], cur[512], psum[16], red[256];
    int p = (int)blockIdx.x, tid = (int)threadIdx.x;
    // self-scan: gbase = sum(gcur[0..p))
    red[tid] = (tid < p && tid < NPART) ? gcur[tid] : 0;
    __syncthreads();
    for (int o = 128; o > 0; o >>= 1) {
        if (tid < o) red[tid] += red[tid + o];
        __syncthreads();
    }
    int gbase = red[0];
    int cntE = gcur[p];
    if (cntE > PSLOT) cntE = PSLOT;
    for (int i = tid; i < 512; i += 256) ncnt[i] = 0;
    __syncthreads();
    const unsigned int* pp = pairs + (size_t)p * PSLOT;
    for (int i = tid; i < cntE; i += 256) atomicAdd(&ncnt[pp[i] >> 17], 1);
    __syncthreads();
    if (tid < 16) {
        int s = 0;
        for (int j = tid * 32; j < tid * 32 + 32; j++) { pre[j] = s; s += ncnt[j]; }
        psum[tid] = s;
    }
    __syncthreads();
    if (tid == 0) {
        int s = 0;
        for (int j = 0; j < 16; j++) { int t = psum[j]; psum[j] = s; s += t; }
    }
    __syncthreads();
    if (tid < 16)
        for (int j = tid * 32; j < tid * 32 + 32; j++) pre[j] += psum[tid];
    __syncthreads();
    for (int j = tid; j < 512; j += 256) {
        cur[j] = pre[j];
        int node = p * 512 + j;
        if (node < GN) {
            indeg[node] = ncnt[j];
            offs[node] = gbase + pre[j];
            dinv[node] = rsqrtf((float)(ncnt[j] + 1));   // +1: self loop
        }
    }
    __syncthreads();
    for (int i = tid; i < cntE; i += 256) {
        unsigned v = pp[i];
        int r = atomicAdd(&cur[v >> 17], 1);
        csr[gbase + r] = (int)(v & 0x1FFFFu);
    }
}

// ---------------- fused agg64 + GEMM1 (64->96) ------------------------------
// 1024 threads = 16 waves = 16 nodes, ONE node per wave (gather TLP kept).
// After barrier, waves 0..5 each compute one 16-col slice of the MFMA.
__global__ __launch_bounds__(1024, 8)
void ar1_ag64g(const void* __restrict__ Xv, const int* __restrict__ offs,
               const int* __restrict__ indeg, const int* __restrict__ csr,
               const float* __restrict__ dinv, const int* __restrict__ flagF,
               const unsigned short* __restrict__ Bp,
               const float* __restrict__ scale, const float* __restrict__ shift,
               unsigned short* __restrict__ C) {
    __shared__ unsigned short AL[16 * 72];
    int tid = (int)threadIdx.x, wv = tid >> 6, lane = tid & 63;
    int nb = (int)blockIdx.x * 16;
    int node = nb + wv;                 // GN = 3125*16 exactly
    int chunk = lane & 7, eslot = lane >> 3;
    int f = flagF[0];
    const unsigned short* X16 = (const unsigned short*)Xv;
    const float* X32 = (const float*)Xv;
    float di = dinv[node];
    int off = offs[node], cnt = indeg[node];

    float acc[8];
#pragma unroll
    for (int j = 0; j < 8; j++) acc[j] = 0.f;

    for (int base = 0; base < cnt; base += 16) {
        int ss[2]; float ww[2];
#pragma unroll
        for (int k = 0; k < 2; k++) {
            int e = base + k * 8 + eslot;
            int s = node; float w = 0.f;
            if (e < cnt) {
                s = csr[off + e];
                if ((unsigned)s >= (unsigned)GN) s = node;
                w = dinv[s] * di;
            }
            ss[k] = s; ww[k] = w;
        }
#pragma unroll
        for (int k = 0; k < 2; k++) {
            float hv[8];
            if (f) {
                floatx4 a = *((const floatx4*)(X32 + (size_t)ss[k] * 64 + chunk * 8));
                floatx4 b = *((const floatx4*)(X32 + (size_t)ss[k] * 64 + chunk * 8 + 4));
#pragma unroll
                for (int j = 0; j < 4; j++) { hv[j] = a[j]; hv[4 + j] = b[j]; }
            } else {
                bf16x8 h = *((const bf16x8*)(X16 + (size_t)ss[k] * 64 + chunk * 8));
#pragma unroll
                for (int j = 0; j < 8; j++) hv[j] = ar1_b2f((unsigned short)h[j]);
            }
#pragma unroll
            for (int j = 0; j < 8; j++) acc[j] += ww[k] * hv[j];
        }
    }
#pragma unroll
    for (int j = 0; j < 8; j++) {
        acc[j] += __shfl_xor(acc[j], 8, 64);
        acc[j] += __shfl_xor(acc[j], 16, 64);
        acc[j] += __shfl_xor(acc[j], 32, 64);
    }
    if (eslot == 0) {
        float hv[8];
        if (f) {
            floatx4 a = *((const floatx4*)(X32 + (size_t)node * 64 + chunk * 8));
            floatx4 b = *((const floatx4*)(X32 + (size_t)node * 64 + chunk * 8 + 4));
#pragma unroll
            for (int j = 0; j < 4; j++) { hv[j] = a[j]; hv[4 + j] = b[j]; }
        } else {
            bf16x8 h = *((const bf16x8*)(X16 + (size_t)node * 64 + chunk * 8));
#pragma unroll
            for (int j = 0; j < 8; j++) hv[j] = ar1_b2f((unsigned short)h[j]);
        }
        bf16x8 o;
#pragma unroll
        for (int j = 0; j < 8; j++)
            o[j] = (short)ar1_f2b(acc[j] + di * di * hv[j]);
        *((bf16x8*)(AL + (size_t)wv * 72 + chunk * 8)) = o;
    }
    __syncthreads();

    if (wv < 6) {                       // GEMM: t = wv, K=64 (nch=2)
        int m = lane & 15, quad = lane >> 4, t = wv;
        floatx4 g = (floatx4){0.f, 0.f, 0.f, 0.f};
#pragma unroll
        for (int c = 0; c < 2; c++) {
            bf16x8 a = *((const bf16x8*)(AL + (size_t)m * 72 + c * 32 + quad * 8));
            bf16x8 bfr = *((const bf16x8*)(Bp + ((size_t)(t * 2 + c) * 64 + lane) * 8));
            g = __builtin_amdgcn_mfma_f32_16x16x32_bf16(a, bfr, g, 0, 0, 0);
        }
#pragma unroll
        for (int r = 0; r < 4; r++) {
            int row = nb + quad * 4 + r;
            int col = t * 16 + m;
            float v = g[r] * scale[col] + shift[col];
            C[(size_t)row * 96 + col] = ar1_f2b(fmaxf(v, 0.f));
        }
    }
}

// ---------------- fused agg96 + GEMM2 (96->96) ------------------------------
__global__ __launch_bounds__(1024, 8)
void ar1_ag96g(const unsigned short* __restrict__ H, const int* __restrict__ offs,
               const int* __restrict__ indeg, const int* __restrict__ csr,
               const float* __restrict__ dinv,
               const unsigned short* __restrict__ Bp,
               const float* __restrict__ scale, const float* __restrict__ shift,
               unsigned short* __restrict__ C) {
    __shared__ unsigned short AL[16 * 104];
    int tid = (int)threadIdx.x, wv = tid >> 6, lane = tid & 63;
    int nb = (int)blockIdx.x * 16;
    int node = nb + wv;
    int chunk = lane % 12, eslot = lane / 12;
    int active = (lane < 48) ? 1 : 0;
    float di = dinv[node];
    int off = offs[node], cnt = indeg[node];

    float acc[8];
#pragma unroll
    for (int j = 0; j < 8; j++) acc[j] = 0.f;

    if (active) {
        for (int base = 0; base < cnt; base += 16) {
            int ss[4]; float ww[4]; bf16x8 hh[4];
#pragma unroll
            for (int k = 0; k < 4; k++) {
                int e = base + k * 4 + eslot;
                int s = node; float w = 0.f;
                if (e < cnt) {
                    s = csr[off + e];
                    if ((unsigned)s >= (unsigned)GN) s = node;
                    w = dinv[s] * di;
                }
                ss[k] = s; ww[k] = w;
            }
#pragma unroll
            for (int k = 0; k < 4; k++)
                hh[k] = *((const bf16x8*)(H + (size_t)ss[k] * 96 + chunk * 8));
#pragma unroll
            for (int k = 0; k < 4; k++)
#pragma unroll
                for (int j = 0; j < 8; j++)
                    acc[j] += ww[k] * ar1_b2f((unsigned short)hh[k][j]);
        }
    }
#pragma unroll
    for (int j = 0; j < 8; j++) {
        float a1 = __shfl(acc[j], lane + 12, 64);
        float a2 = __shfl(acc[j], lane + 24, 64);
        float a3 = __shfl(acc[j], lane + 36, 64);
        acc[j] += a1 + a2 + a3;
    }
    if (lane < 12) {
        bf16x8 hs = *((const bf16x8*)(H + (size_t)node * 96 + chunk * 8));
        bf16x8 o;
#pragma unroll
        for (int j = 0; j < 8; j++)
            o[j] = (short)ar1_f2b(acc[j] + di * di * ar1_b2f((unsigned short)hs[j]));
        *((bf16x8*)(AL + (size_t)wv * 104 + chunk * 8)) = o;
    }
    __syncthreads();

    if (wv < 6) {                       // GEMM: t = wv, K=96 (nch=3)
        int m = lane & 15, quad = lane >> 4, t = wv;
        floatx4 g = (floatx4){0.f, 0.f, 0.f, 0.f};
#pragma unroll
        for (int c = 0; c < 3; c++) {
            bf16x8 a = *((const bf16x8*)(AL + (size_t)m * 104 + c * 32 + quad * 8));
            bf16x8 bfr = *((const bf16x8*)(Bp + ((size_t)(t * 3 + c) * 64 + lane) * 8));
            g = __builtin_amdgcn_mfma_f32_16x16x32_bf16(a, bfr, g, 0, 0, 0);
        }
#pragma unroll
        for (int r = 0; r < 4; r++) {
            int row = nb + quad * 4 + r;
            int col = t * 16 + m;
            float v = g[r] * scale[col] + shift[col];
            C[(size_t)row * 96 + col] = ar1_f2b(fmaxf(v, 0.f));
        }
    }
}

// ---------------- plain agg96 (layer 3; GEMM3 lives in mlp2) ----------------
__global__ __launch_bounds__(256, 8)
void ar1_agg96(const unsigned short* __restrict__ H, const int* __restrict__ offs,
               const int* __restrict__ indeg, const int* __restrict__ csr,
               const float* __restrict__ dinv, unsigned short* __restrict__ Out) {
    int wv = (int)threadIdx.x >> 6, lane = (int)threadIdx.x & 63;
    int node = (int)blockIdx.x * 4 + wv;
    if (node >= GN) return;
    int chunk = lane % 12;
    int eslot = lane / 12;
    int active = (lane < 48) ? 1 : 0;
    float di = dinv[node];
    int off = offs[node], cnt = indeg[node];

    float acc[8];
#pragma unroll
    for (int j = 0; j < 8; j++) acc[j] = 0.f;

    if (active) {
        for (int base = 0; base < cnt; base += 16) {
            int ss[4]; float ww[4]; bf16x8 hh[4];
#pragma unroll
            for (int k = 0; k < 4; k++) {
                int e = base + k * 4 + eslot;
                int s = node; float w = 0.f;
                if (e < cnt) {
                    s = csr[off + e];
                    if ((unsigned)s >= (unsigned)GN) s = node;
                    w = dinv[s] * di;
                }
                ss[k] = s; ww[k] = w;
            }
#pragma unroll
            for (int k = 0; k < 4; k++)
                hh[k] = *((const bf16x8*)(H + (size_t)ss[k] * 96 + chunk * 8));
#pragma unroll
            for (int k = 0; k < 4; k++)
#pragma unroll
                for (int j = 0; j < 8; j++)
                    acc[j] += ww[k] * ar1_b2f((unsigned short)hh[k][j]);
        }
    }
#pragma unroll
    for (int j = 0; j < 8; j++) {
        float a1 = __shfl(acc[j], lane + 12, 64);
        float a2 = __shfl(acc[j], lane + 24, 64);
        float a3 = __shfl(acc[j], lane + 36, 64);
        acc[j] += a1 + a2 + a3;
    }
    if (lane < 12) {
        bf16x8 hs = *((const bf16x8*)(H + (size_t)node * 96 + chunk * 8));
#pragma unroll
        for (int j = 0; j < 8; j++) {
            float v = acc[j] + di * di * ar1_b2f((unsigned short)hs[j]);
            Out[(size_t)node * 96 + chunk * 8 + j] = ar1_f2b(v);
        }
    }
}

// ---------------- fused GEMM3 + MLP: 96->96 then 96->256->128->64->8 --------
__global__ __launch_bounds__(256, 2)
void ar1_mlp2(const unsigned short* __restrict__ A,   // layer-3 agg, stride 96
              const unsigned short* __restrict__ b2w, // gemm3 weights (packed)
              const float* __restrict__ sc3, const float* __restrict__ sh3,
              const unsigned short* __restrict__ b3,
              const unsigned short* __restrict__ b4,
              const unsigned short* __restrict__ b5,
              const unsigned short* __restrict__ b6,
              const float* __restrict__ lb0, const float* __restrict__ lb1,
              const float* __restrict__ lb2, const float* __restrict__ lb3,
              void* __restrict__ out, const int* __restrict__ f32out) {
    __shared__ unsigned short SH[16896 + 13312];      // H1 | union(H0 / H2+H3)
    unsigned short* H1 = SH;                          // 64 x 264 (256 cols)
    unsigned short* H0 = SH + 16896;                  // 64 x 104 (96 cols)
    unsigned short* H2 = SH + 16896;                  // 64 x 136 (128 cols)
    unsigned short* H3 = SH + 16896 + 8704;           // 64 x 72  (64 cols)
    int tid = (int)threadIdx.x, wv = tid >> 6, lane = tid & 63;
    int m = lane & 15, quad = lane >> 4;
    int mb = (int)blockIdx.x * 64 + wv * 16;
    int lwv = wv * 16;

    // ---- stage 0: GCN layer-3 GEMM 96 -> 96 (nch=3, NT=6), affine+ReLU ----
    {
        int arow = mb + m; if (arow >= GN) arow = GN - 1;
        const unsigned short* Ap = A + (size_t)arow * 96 + quad * 8;
        floatx4 acc[6];
#pragma unroll
        for (int t = 0; t < 6; t++) acc[t] = (floatx4){0.f, 0.f, 0.f, 0.f};
        for (int c = 0; c < 3; c++) {
            bf16x8 a = *((const bf16x8*)(Ap + c * 32));
#pragma unroll
            for (int t = 0; t < 6; t++) {
                bf16x8 b = *((const bf16x8*)(b2w + ((size_t)(t * 3 + c) * 64 + lane) * 8));
                acc[t] = __builtin_amdgcn_mfma_f32_16x16x32_bf16(a, b, acc[t], 0, 0, 0);
            }
        }
#pragma unroll
        for (int t = 0; t < 6; t++)
#pragma unroll
            for (int r = 0; r < 4; r++) {
                int lr = lwv + quad * 4 + r, col = t * 16 + m;
                float v = acc[t][r] * sc3[col] + sh3[col];
                H0[lr * 104 + col] = ar1_f2b(fmaxf(v, 0.f));
            }
    }
    // ---- layer 1: 96 -> 256 (nch=3, NT=16), from H0 ----
    {
        const unsigned short* Hp = H0 + (size_t)(lwv + m) * 104 + quad * 8;
        floatx4 acc[16];
#pragma unroll
        for (int t = 0; t < 16; t++) acc[t] = (floatx4){0.f, 0.f, 0.f, 0.f};
        for (int c = 0; c < 3; c++) {
            bf16x8 a = *((const bf16x8*)(Hp + c * 32));
#pragma unroll
            for (int t = 0; t < 16; t++) {
                bf16x8 b = *((const bf16x8*)(b3 + ((size_t)(t * 3 + c) * 64 + lane) * 8));
                acc[t] = __builtin_amdgcn_mfma_f32_16x16x32_bf16(a, b, acc[t], 0, 0, 0);
            }
        }
#pragma unroll
        for (int t = 0; t < 16; t++)
#pragma unroll
            for (int r = 0; r < 4; r++) {
                int lr = lwv + quad * 4 + r, col = t * 16 + m;
                H1[lr * 264 + col] = ar1_f2b(fmaxf(acc[t][r] + lb0[col], 0.f));
            }
    }
    // ---- layer 2: 256 -> 128 (nch=8, NT=8) ---- (H0 dead; H2 overwrites it)
    {
        const unsigned short* Hp = H1 + (size_t)(lwv + m) * 264 + quad * 8;
        floatx4 acc[8];
#pragma unroll
        for (int t = 0; t < 8; t++) acc[t] = (floatx4){0.f, 0.f, 0.f, 0.f};
        for (int c = 0; c < 8; c++) {
            bf16x8 a = *((const bf16x8*)(Hp + c * 32));
#pragma unroll
            for (int t = 0; t < 8; t++) {
                bf16x8 b = *((const bf16x8*)(b4 + ((size_t)(t * 8 + c) * 64 + lane) * 8));
                acc[t] = __builtin_amdgcn_mfma_f32_16x16x32_bf16(a, b, acc[t], 0, 0, 0);
            }
        }
#pragma unroll
        for (int t = 0; t < 8; t++)
#pragma unroll
            for (int r = 0; r < 4; r++) {
                int lr = lwv + quad * 4 + r, col = t * 16 + m;
                H2[lr * 136 + col] = ar1_f2b(fmaxf(acc[t][r] + lb1[col], 0.f));
            }
    }
    // ---- layer 3: 128 -> 64 (nch=4, NT=4) ----
    {
        const unsigned short* Hp = H2 + (size_t)(lwv + m) * 136 + quad * 8;
        floatx4 acc[4];
#pragma unroll
        for (int t = 0; t < 4; t++) acc[t] = (floatx4){0.f, 0.f, 0.f, 0.f};
        for (int c = 0; c < 4; c++) {
            bf16x8 a = *((const bf16x8*)(Hp + c * 32));
#pragma unroll
            for (int t = 0; t < 4; t++) {
                bf16x8 b = *((const bf16x8*)(b5 + ((size_t)(t * 4 + c) * 64 + lane) * 8));
                acc[t] = __builtin_amdgcn_mfma_f32_16x16x32_bf16(a, b, acc[t], 0, 0, 0);
            }
        }
#pragma unroll
        for (int t = 0; t < 4; t++)
#pragma unroll
            for (int r = 0; r < 4; r++) {
                int lr = lwv + quad * 4 + r, col = t * 16 + m;
                H3[lr * 72 + col] = ar1_f2b(fmaxf(acc[t][r] + lb2[col], 0.f));
            }
    }
    // ---- layer 4: 64 -> 8 (nch=2, NT=1, M padded 16) ----
    {
        const unsigned short* Hp = H3 + (size_t)(lwv + m) * 72 + quad * 8;
        floatx4 acc = (floatx4){0.f, 0.f, 0.f, 0.f};
        for (int c = 0; c < 2; c++) {
            bf16x8 a = *((const bf16x8*)(Hp + c * 32));
            bf16x8 b = *((const bf16x8*)(b6 + ((size_t)c * 64 + lane) * 8));
            acc = __builtin_amdgcn_mfma_f32_16x16x32_bf16(a, b, acc, 0, 0, 0);
        }
        int wf32 = f32out[0];
#pragma unroll
        for (int r = 0; r < 4; r++) {
            int row = mb + quad * 4 + r;
            if (row < GN && m < 8) {
                float v = acc[r] + lb3[m];
                if (wf32) ((float*)out)[(size_t)row * 8 + m] = v;
                else ((unsigned short*)out)[(size_t)row * 8 + m] = ar1_f2b(v);
            }
        }
    }
}

extern "C" void kernel_launch(void* const* d_in, const int* in_sizes, int n_in,
                              void* d_out, int out_size, void* d_ws, size_t ws_size,
                              hipStream_t stream) {
    (void)in_sizes; (void)n_in; (void)out_size;

    // workspace layout
    char* p = (char*)d_ws;
    unsigned short* bufA = (unsigned short*)p; p += (size_t)GN * 96 * 2;   // 9.6 MB
    unsigned short* bufB = (unsigned short*)p; p += (size_t)GN * 96 * 2;   // 9.6 MB
    unsigned short* bufC = (unsigned short*)p; p += (size_t)GN * 96 * 2;   // 9.6 MB
    unsigned int* pairs = (unsigned int*)p; p += (size_t)NPART * PSLOT * 4; // 3.6 MB
    int* indeg  = (int*)p;    p += (size_t)GN * 4;
    int* offs   = (int*)p;    p += (size_t)GN * 4;
    float* dinv = (float*)p;  p += (size_t)GN * 4;
    int* csr    = (int*)p;    p += (size_t)GE * 4;
    int* gcur   = (int*)p;    p += 1024;
    int* flagI  = (int*)p;    p += 1024;
    int* flagF  = (int*)p;    p += 1024;
    unsigned short* bpArena = (unsigned short*)p; p += 91136 * 2;  // packed W
    float* fArena = (float*)p; p += 2048 * 4;                      // small fp32
    size_t need = (size_t)(p - (char*)d_ws);
    if (ws_size < need) {
        hipMemsetAsync(d_out, 0x41, (size_t)GN * 8 * 2, stream);  // marker 12.06
        return;
    }

    // packed-weight arena offsets (shorts): w1,w2,w3,lw1,lw2,lw3,lw4
    unsigned short* bp[7];
    int bpn[7] = {6144, 9216, 9216, 24576, 32768, 8192, 1024};
    {
        unsigned short* q = bpArena;
        for (int i = 0; i < 7; i++) { bp[i] = q; q += bpn[i]; }
    }

    // small fp32 arena: lb1(256),lb2(128),lb3(64),lb4(8), 6 x 96 scale/shift
    float* lb[4]; float* ss[6];
    {
        float* q = fArena;
        int ln[4] = {256, 128, 64, 8};
        for (int i = 0; i < 4; i++) { lb[i] = q; q += ln[i]; }
        for (int i = 0; i < 6; i++) { ss[i] = q; q += 96; }
    }

    const int* ei = (const int*)d_in[1];
    const unsigned short* xw = (const unsigned short*)d_in[0];

    // graph build + weight prep: memset, merged kernel, csr
    hipMemsetAsync(gcur, 0, NPART * 4, stream);
    {
        PackAll pa;
        int wsrc[7] = {2, 6, 10, 14, 16, 18, 20};
        int Ks[7] = {64, 96, 96, 96, 256, 128, 64};
        int Ms[7] = {96, 96, 96, 256, 128, 64, 8};
        int cum = 0;
        for (int i = 0; i < 7; i++) {
            pa.src[i] = d_in[wsrc[i]]; pa.dst[i] = bp[i];
            pa.K[i] = Ks[i]; pa.M[i] = Ms[i];
            pa.start[i] = cum;
            cum += (Ms[i] + 15) / 16 * (Ks[i] / 32);
        }
        pa.start[7] = cum;   // 178
        SmallCvt sc;
        int lsrc[4] = {15, 17, 19, 21};
        int ln[4] = {256, 128, 64, 8};
        for (int i = 0; i < 4; i++) { sc.src[i] = d_in[lsrc[i]]; sc.dst[i] = lb[i]; sc.n[i] = ln[i]; }
        int gsrc[9] = {3, 4, 5, 7, 8, 9, 11, 12, 13};
        for (int i = 0; i < 9; i++) sc.gb[i] = d_in[gsrc[i]];
        for (int i = 0; i < 6; i++) sc.ss[i] = ss[i];
        Arthur1_16458314678864_kernel<<<437, 256, 0, stream>>>(
            pa, sc, ei, xw, flagI, flagF, gcur, pairs);
    }
    ar1_csr<<<NPART, 256, 0, stream>>>(pairs, gcur, csr, indeg, offs, dinv);

    const int GB = (GN + 63) / 64;    // 782 (mlp2)
    const int AB = GN / 4;            // 12500 (plain agg96)
    const int FB = GN / 16;           // 3125 (fused agg+gemm, 1024 thr)

    // GCN: fused agg+GEMM layers 1,2; plain agg for layer 3 (GEMM3 in mlp2)
    ar1_ag64g<<<FB, 1024, 0, stream>>>(d_in[0], offs, indeg, csr, dinv, flagF,
                                       bp[0], ss[0], ss[1], bufA);
    ar1_ag96g<<<FB, 1024, 0, stream>>>(bufA, offs, indeg, csr, dinv,
                                       bp[1], ss[2], ss[3], bufB);
    ar1_agg96<<<AB, 256, 0, stream>>>(bufB, offs, indeg, csr, dinv, bufC);

    // fused GEMM3 + MLP -> d_out (fp32/bf16 per flagF)
    ar1_mlp2<<<GB, 256, 0, stream>>>(bufC, bp[2], ss[4], ss[5],
                                     bp[3], bp[4], bp[5], bp[6],
                                     lb[0], lb[1], lb[2], lb[3], d_out, flagF);
}

// Round 21
// 291.964 us; speedup vs baseline: 1.4227x; 1.0028x over previous
//
#include <hip/hip_runtime.h>

// GCN(3 layers) + MLP(4 layers), N=50000, E=800000, out = N x 8 bf16.
// NOTE: do NOT include <hip/hip_bf16.h> — breaks this harness's build
// (rounds 1-4 fell back to a stub; round 5 proved it). Manual bf16 ushort ops.
// Dtype runtime-detection: flagI (edge_index int64 vs int32), flagF (floats
// fp32 vs packed bf16) — self-detected per block via butterfly reduce.
//
// R21: layer-3 agg + GEMM3 + whole MLP fused into ONE 1024-thread kernel
// (R20 recipe: 16 waves = 16 nodes, ONE node per wave for the gather —
// TLP preserved — then barriered compute phases where waves cover column
// slices: GEMM3 waves 0-5, MLP L1 all 16, L2 waves 0-7, L3 0-3, L4 wave 0
// -> d_out). Kills plain agg96 + mlp2 dispatches and the 19 MB bufC round
// trip. LDS 21.3 KB/block, 2 blocks/CU. Everything else from R20 kept
// (fused ag64g/ag96g, merged prep kernel, partition-sort CSR).

#define GN 50000
#define GE 800000
#define NPART 98        // partitions of 512 dst nodes
#define PSLOT 9216      // slab capacity per partition (mean 8163, +11 sigma)
#define CHK 2048        // edges per block in pass 1

typedef __attribute__((ext_vector_type(8))) short bf16x8;
typedef __attribute__((ext_vector_type(4))) float floatx4;

__device__ __forceinline__ float ar1_b2f(unsigned short h) {
    return __uint_as_float(((unsigned)h) << 16);
}
__device__ __forceinline__ unsigned short ar1_f2b(float f) {
    unsigned u = __float_as_uint(f);
    u = u + 0x7FFFu + ((u >> 16) & 1u);   // round-to-nearest-even
    return (unsigned short)(u >> 16);
}

// wave-parallel detectors (4 loads + butterfly; every wave gets the answer)
__device__ __forceinline__ int ar1_det64(const int* ei) {
    int l = (int)threadIdx.x & 63;
    int nz = 0;
#pragma unroll
    for (int k = 0; k < 4; k++)
        nz += (ei[2 * (l + 64 * k) + 1] != 0) ? 1 : 0;
#pragma unroll
    for (int o = 1; o < 64; o <<= 1)
        nz += __shfl_xor(nz, o, 64);
    return (nz < 8) ? 1 : 0;                 // 1 => int64
}
__device__ __forceinline__ int ar1_detf32(const unsigned short* xw) {
    int l = (int)threadIdx.x & 63;
    int c = 0;
#pragma unroll
    for (int k = 0; k < 4; k++) {
        unsigned short w = xw[2 * (l + 64 * k)];
        int ex = (w >> 7) & 0xFF;
        if (w == 0 || (ex >= 90 && ex <= 150)) c++;
    }
#pragma unroll
    for (int o = 1; o < 64; o <<= 1)
        c += __shfl_xor(c, o, 64);
    return (c > 200) ? 0 : 1;                // 1 => fp32
}

struct PackAll {
    const void* src[7];
    unsigned short* dst[7];
    int K[7], M[7], start[8];
};
struct SmallCvt {
    const void* src[4];   // lb1, lb2, lb3, lb4
    float* dst[4];
    int n[4];
    const void* gb[9];    // b1,g1,be1, b2,g2,be2, b3,g3,be3
    float* ss[6];         // scale1,shift1, ...
};

// merged prep (carries harness kernel name), grid = 391 + 45 + 1 = 437:
//  b<391: edge partition pass (self-detected is64); needs gcur pre-zeroed.
//  b<436: pack 4 MFMA B-fragments each (self-detected flagF).
//  b==436: small cvt + BN fold; writes flagI/flagF for downstream kernels.
__global__ __launch_bounds__(256)
void Arthur1_16458314678864_kernel(PackAll pa, SmallCvt sc,
                                   const int* __restrict__ ei,
                                   const unsigned short* __restrict__ xw,
                                   int* flagI, int* flagF,
                                   int* __restrict__ gcur,
                                   unsigned int* __restrict__ pairs) {
    int b = (int)blockIdx.x;
    int tid = (int)threadIdx.x;
    if (b < 391) {
        __shared__ int cnt[NPART], base[NPART], cur[NPART];
        for (int i = tid; i < NPART; i += 256) { cnt[i] = 0; cur[i] = 0; }
        int is64 = ar1_det64(ei);
        __syncthreads();
        int e0 = b * CHK;
        unsigned pk[8]; int q[8];
#pragma unroll
        for (int k = 0; k < 8; k++) {
            int e = e0 + k * 256 + tid;
            q[k] = -1; pk[k] = 0;
            if (e < GE) {
                int s = is64 ? ei[2 * e] : ei[e];
                int d = is64 ? ei[2 * (GE + e)] : ei[GE + e];
                if ((unsigned)s < (unsigned)GN && (unsigned)d < (unsigned)GN) {
                    int qq = d >> 9;
                    q[k] = qq;
                    pk[k] = (unsigned)s | ((unsigned)(d & 511) << 17);
                    atomicAdd(&cnt[qq], 1);
                }
            }
        }
        __syncthreads();
        for (int i = tid; i < NPART; i += 256)
            base[i] = (cnt[i] > 0) ? atomicAdd(&gcur[i], cnt[i]) : 0;
        __syncthreads();
#pragma unroll
        for (int k = 0; k < 8; k++) {
            if (q[k] >= 0) {
                int r = base[q[k]] + atomicAdd(&cur[q[k]], 1);
                if (r < PSLOT) pairs[(size_t)q[k] * PSLOT + r] = pk[k];
            }
        }
    } else if (b < 436) {
        int f = ar1_detf32(xw);
        int frag_g = (b - 391) * 4 + (tid >> 6);
        if (frag_g >= 178) return;
        int w = 0;
        while (w < 6 && frag_g >= pa.start[w + 1]) w++;
        int frag = frag_g - pa.start[w];
        int K = pa.K[w], M = pa.M[w];
        int lane = tid & 63;
        int nch = K >> 5;
        int t = frag / nch, c = frag - t * nch;
        int n = t * 16 + (lane & 15);
        int k0 = c * 32 + (lane >> 4) * 8;
        unsigned short* o = pa.dst[w] + ((size_t)frag * 64 + lane) * 8;
        for (int j = 0; j < 8; j++) {
            unsigned short v = 0;
            if (n < M) {
                int idx = (k0 + j) * M + n;
                v = f ? ar1_f2b(((const float*)pa.src[w])[idx])
                      : ((const unsigned short*)pa.src[w])[idx];
            }
            o[j] = v;
        }
    } else {
        int f = ar1_detf32(xw);
        int i64 = ar1_det64(ei);
        if (tid == 0) { flagI[0] = i64; flagF[0] = f; }
        const float C = 0.9999950000374997f;   // 1/sqrt(1+1e-5)
        for (int s = 0; s < 4; s++) {
            for (int i = tid; i < sc.n[s]; i += 256) {
                float v = f ? ((const float*)sc.src[s])[i]
                            : ar1_b2f(((const unsigned short*)sc.src[s])[i]);
                sc.dst[s][i] = v;
            }
        }
        for (int k = 0; k < 3; k++) {
            for (int i = tid; i < 96; i += 256) {
                float bb, g, be;
                if (f) {
                    bb = ((const float*)sc.gb[3 * k + 0])[i];
                    g  = ((const float*)sc.gb[3 * k + 1])[i];
                    be = ((const float*)sc.gb[3 * k + 2])[i];
                } else {
                    bb = ar1_b2f(((const unsigned short*)sc.gb[3 * k + 0])[i]);
                    g  = ar1_b2f(((const unsigned short*)sc.gb[3 * k + 1])[i]);
                    be = ar1_b2f(((const unsigned short*)sc.gb[3 * k + 2])[i]);
                }
                sc.ss[2 * k + 0][i] = C * g;
                sc.ss[2 * k + 1][i] = bb * C * g + be;
            }
        }
    }
}

// per-partition -> contiguous CSR slice + indeg/offs/dinv (self-scans gbase)
__global__ __launch_bounds__(256)
void ar1_csr(const unsigned int* __restrict__ pairs, const int* __restrict__ gcur,
             int* __restrict__ csr, int* __restrict__ indeg,
             int* __restrict__ offs, float* __restrict__ dinv) {
    __shared__ int ncnt[512], pre[512], cur[512], psum[16], red[256];
    int p = (int)blockIdx.x, tid = (int)threadIdx.x;
    red[tid] = (tid < p && tid < NPART) ? gcur[tid] : 0;
    __syncthreads();
    for (int o = 128; o > 0; o >>= 1) {
        if (tid < o) red[tid] += red[tid + o];
        __syncthreads();
    }
    int gbase = red[0];
    int cntE = gcur[p];
    if (cntE > PSLOT) cntE = PSLOT;
    for (int i = tid; i < 512; i += 256) ncnt[i] = 0;
    __syncthreads();
    const unsigned int* pp = pairs + (size_t)p * PSLOT;
    for (int i = tid; i < cntE; i += 256) atomicAdd(&ncnt[pp[i] >> 17], 1);
    __syncthreads();
    if (tid < 16) {
        int s = 0;
        for (int j = tid * 32; j < tid * 32 + 32; j++) { pre[j] = s; s += ncnt[j]; }
        psum[tid] = s;
    }
    __syncthreads();
    if (tid == 0) {
        int s = 0;
        for (int j = 0; j < 16; j++) { int t = psum[j]; psum[j] = s; s += t; }
    }
    __syncthreads();
    if (tid < 16)
        for (int j = tid * 32; j < tid * 32 + 32; j++) pre[j] += psum[tid];
    __syncthreads();
    for (int j = tid; j < 512; j += 256) {
        cur[j] = pre[j];
        int node = p * 512 + j;
        if (node < GN) {
            indeg[node] = ncnt[j];
            offs[node] = gbase + pre[j];
            dinv[node] = rsqrtf((float)(ncnt[j] + 1));   // +1: self loop
        }
    }
    __syncthreads();
    for (int i = tid; i < cntE; i += 256) {
        unsigned v = pp[i];
        int r = atomicAdd(&cur[v >> 17], 1);
        csr[gbase + r] = (int)(v & 0x1FFFFu);
    }
}

// ---------------- fused agg64 + GEMM1 (64->96) ------------------------------
// 1024 threads = 16 waves = 16 nodes, ONE node per wave (gather TLP kept).
__global__ __launch_bounds__(1024, 8)
void ar1_ag64g(const void* __restrict__ Xv, const int* __restrict__ offs,
               const int* __restrict__ indeg, const int* __restrict__ csr,
               const float* __restrict__ dinv, const int* __restrict__ flagF,
               const unsigned short* __restrict__ Bp,
               const float* __restrict__ scale, const float* __restrict__ shift,
               unsigned short* __restrict__ C) {
    __shared__ unsigned short AL[16 * 72];
    int tid = (int)threadIdx.x, wv = tid >> 6, lane = tid & 63;
    int nb = (int)blockIdx.x * 16;
    int node = nb + wv;                 // GN = 3125*16 exactly
    int chunk = lane & 7, eslot = lane >> 3;
    int f = flagF[0];
    const unsigned short* X16 = (const unsigned short*)Xv;
    const float* X32 = (const float*)Xv;
    float di = dinv[node];
    int off = offs[node], cnt = indeg[node];

    float acc[8];
#pragma unroll
    for (int j = 0; j < 8; j++) acc[j] = 0.f;

    for (int base = 0; base < cnt; base += 16) {
        int ss[2]; float ww[2];
#pragma unroll
        for (int k = 0; k < 2; k++) {
            int e = base + k * 8 + eslot;
            int s = node; float w = 0.f;
            if (e < cnt) {
                s = csr[off + e];
                if ((unsigned)s >= (unsigned)GN) s = node;
                w = dinv[s] * di;
            }
            ss[k] = s; ww[k] = w;
        }
#pragma unroll
        for (int k = 0; k < 2; k++) {
            float hv[8];
            if (f) {
                floatx4 a = *((const floatx4*)(X32 + (size_t)ss[k] * 64 + chunk * 8));
                floatx4 b = *((const floatx4*)(X32 + (size_t)ss[k] * 64 + chunk * 8 + 4));
#pragma unroll
                for (int j = 0; j < 4; j++) { hv[j] = a[j]; hv[4 + j] = b[j]; }
            } else {
                bf16x8 h = *((const bf16x8*)(X16 + (size_t)ss[k] * 64 + chunk * 8));
#pragma unroll
                for (int j = 0; j < 8; j++) hv[j] = ar1_b2f((unsigned short)h[j]);
            }
#pragma unroll
            for (int j = 0; j < 8; j++) acc[j] += ww[k] * hv[j];
        }
    }
#pragma unroll
    for (int j = 0; j < 8; j++) {
        acc[j] += __shfl_xor(acc[j], 8, 64);
        acc[j] += __shfl_xor(acc[j], 16, 64);
        acc[j] += __shfl_xor(acc[j], 32, 64);
    }
    if (eslot == 0) {
        float hv[8];
        if (f) {
            floatx4 a = *((const floatx4*)(X32 + (size_t)node * 64 + chunk * 8));
            floatx4 b = *((const floatx4*)(X32 + (size_t)node * 64 + chunk * 8 + 4));
#pragma unroll
            for (int j = 0; j < 4; j++) { hv[j] = a[j]; hv[4 + j] = b[j]; }
        } else {
            bf16x8 h = *((const bf16x8*)(X16 + (size_t)node * 64 + chunk * 8));
#pragma unroll
            for (int j = 0; j < 8; j++) hv[j] = ar1_b2f((unsigned short)h[j]);
        }
        bf16x8 o;
#pragma unroll
        for (int j = 0; j < 8; j++)
            o[j] = (short)ar1_f2b(acc[j] + di * di * hv[j]);
        *((bf16x8*)(AL + (size_t)wv * 72 + chunk * 8)) = o;
    }
    __syncthreads();

    if (wv < 6) {                       // GEMM: t = wv, K=64 (nch=2)
        int m = lane & 15, quad = lane >> 4, t = wv;
        floatx4 g = (floatx4){0.f, 0.f, 0.f, 0.f};
#pragma unroll
        for (int c = 0; c < 2; c++) {
            bf16x8 a = *((const bf16x8*)(AL + (size_t)m * 72 + c * 32 + quad * 8));
            bf16x8 bfr = *((const bf16x8*)(Bp + ((size_t)(t * 2 + c) * 64 + lane) * 8));
            g = __builtin_amdgcn_mfma_f32_16x16x32_bf16(a, bfr, g, 0, 0, 0);
        }
#pragma unroll
        for (int r = 0; r < 4; r++) {
            int row = nb + quad * 4 + r;
            int col = t * 16 + m;
            float v = g[r] * scale[col] + shift[col];
            C[(size_t)row * 96 + col] = ar1_f2b(fmaxf(v, 0.f));
        }
    }
}

// ---------------- fused agg96 + GEMM2 (96->96) ------------------------------
__global__ __launch_bounds__(1024, 8)
void ar1_ag96g(const unsigned short* __restrict__ H, const int* __restrict__ offs,
               const int* __restrict__ indeg, const int* __restrict__ csr,
               const float* __restrict__ dinv,
               const unsigned short* __restrict__ Bp,
               const float* __restrict__ scale, const float* __restrict__ shift,
               unsigned short* __restrict__ C) {
    __shared__ unsigned short AL[16 * 104];
    int tid = (int)threadIdx.x, wv = tid >> 6, lane = tid & 63;
    int nb = (int)blockIdx.x * 16;
    int node = nb + wv;
    int chunk = lane % 12, eslot = lane / 12;
    int active = (lane < 48) ? 1 : 0;
    float di = dinv[node];
    int off = offs[node], cnt = indeg[node];

    float acc[8];
#pragma unroll
    for (int j = 0; j < 8; j++) acc[j] = 0.f;

    if (active) {
        for (int base = 0; base < cnt; base += 16) {
            int ss[4]; float ww[4]; bf16x8 hh[4];
#pragma unroll
            for (int k = 0; k < 4; k++) {
                int e = base + k * 4 + eslot;
                int s = node; float w = 0.f;
                if (e < cnt) {
                    s = csr[off + e];
                    if ((unsigned)s >= (unsigned)GN) s = node;
                    w = dinv[s] * di;
                }
                ss[k] = s; ww[k] = w;
            }
#pragma unroll
            for (int k = 0; k < 4; k++)
                hh[k] = *((const bf16x8*)(H + (size_t)ss[k] * 96 + chunk * 8));
#pragma unroll
            for (int k = 0; k < 4; k++)
#pragma unroll
                for (int j = 0; j < 8; j++)
                    acc[j] += ww[k] * ar1_b2f((unsigned short)hh[k][j]);
        }
    }
#pragma unroll
    for (int j = 0; j < 8; j++) {
        float a1 = __shfl(acc[j], lane + 12, 64);
        float a2 = __shfl(acc[j], lane + 24, 64);
        float a3 = __shfl(acc[j], lane + 36, 64);
        acc[j] += a1 + a2 + a3;
    }
    if (lane < 12) {
        bf16x8 hs = *((const bf16x8*)(H + (size_t)node * 96 + chunk * 8));
        bf16x8 o;
#pragma unroll
        for (int j = 0; j < 8; j++)
            o[j] = (short)ar1_f2b(acc[j] + di * di * ar1_b2f((unsigned short)hs[j]));
        *((bf16x8*)(AL + (size_t)wv * 104 + chunk * 8)) = o;
    }
    __syncthreads();

    if (wv < 6) {                       // GEMM: t = wv, K=96 (nch=3)
        int m = lane & 15, quad = lane >> 4, t = wv;
        floatx4 g = (floatx4){0.f, 0.f, 0.f, 0.f};
#pragma unroll
        for (int c = 0; c < 3; c++) {
            bf16x8 a = *((const bf16x8*)(AL + (size_t)m * 104 + c * 32 + quad * 8));
            bf16x8 bfr = *((const bf16x8*)(Bp + ((size_t)(t * 3 + c) * 64 + lane) * 8));
            g = __builtin_amdgcn_mfma_f32_16x16x32_bf16(a, bfr, g, 0, 0, 0);
        }
#pragma unroll
        for (int r = 0; r < 4; r++) {
            int row = nb + quad * 4 + r;
            int col = t * 16 + m;
            float v = g[r] * scale[col] + shift[col];
            C[(size_t)row * 96 + col] = ar1_f2b(fmaxf(v, 0.f));
        }
    }
}

// ---------------- fused agg96 + GEMM3 + full MLP -> d_out -------------------
// 16 waves = 16 nodes; one node per wave gather into AL; then barriered
// compute phases: GEMM3 (waves 0-5), L1 96->256 (all 16), L2 256->128
// (waves 0-7), L3 128->64 (waves 0-3), L4 64->8 (wave 0 -> out).
__global__ __launch_bounds__(1024, 8)
void ar1_agmlp(const unsigned short* __restrict__ H, const int* __restrict__ offs,
               const int* __restrict__ indeg, const int* __restrict__ csr,
               const float* __restrict__ dinv,
               const unsigned short* __restrict__ b2w,
               const float* __restrict__ sc3, const float* __restrict__ sh3,
               const unsigned short* __restrict__ b3,
               const unsigned short* __restrict__ b4,
               const unsigned short* __restrict__ b5,
               const unsigned short* __restrict__ b6,
               const float* __restrict__ lb0, const float* __restrict__ lb1,
               const float* __restrict__ lb2, const float* __restrict__ lb3,
               void* __restrict__ out, const int* __restrict__ f32out) {
    __shared__ unsigned short AL[16 * 104];   // aggregate rows
    __shared__ unsigned short H0[16 * 104];   // gemm3 out (96 cols)
    __shared__ unsigned short H1[16 * 264];   // 256 cols
    __shared__ unsigned short H2[16 * 136];   // 128 cols
    __shared__ unsigned short H3[16 * 72];    // 64 cols
    int tid = (int)threadIdx.x, wv = tid >> 6, lane = tid & 63;
    int nb = (int)blockIdx.x * 16;
    int node = nb + wv;
    int m = lane & 15, quad = lane >> 4;

    // ---- gather phase (one node per wave) ----
    {
        int chunk = lane % 12, eslot = lane / 12;
        int active = (lane < 48) ? 1 : 0;
        float di = dinv[node];
        int off = offs[node], cnt = indeg[node];
        float acc[8];
#pragma unroll
        for (int j = 0; j < 8; j++) acc[j] = 0.f;
        if (active) {
            for (int base = 0; base < cnt; base += 16) {
                int ss[4]; float ww[4]; bf16x8 hh[4];
#pragma unroll
                for (int k = 0; k < 4; k++) {
                    int e = base + k * 4 + eslot;
                    int s = node; float w = 0.f;
                    if (e < cnt) {
                        s = csr[off + e];
                        if ((unsigned)s >= (unsigned)GN) s = node;
                        w = dinv[s] * di;
                    }
                    ss[k] = s; ww[k] = w;
                }
#pragma unroll
                for (int k = 0; k < 4; k++)
                    hh[k] = *((const bf16x8*)(H + (size_t)ss[k] * 96 + chunk * 8));
#pragma unroll
                for (int k = 0; k < 4; k++)
#pragma unroll
                    for (int j = 0; j < 8; j++)
                        acc[j] += ww[k] * ar1_b2f((unsigned short)hh[k][j]);
            }
        }
#pragma unroll
        for (int j = 0; j < 8; j++) {
            float a1 = __shfl(acc[j], lane + 12, 64);
            float a2 = __shfl(acc[j], lane + 24, 64);
            float a3 = __shfl(acc[j], lane + 36, 64);
            acc[j] += a1 + a2 + a3;
        }
        if (lane < 12) {
            bf16x8 hs = *((const bf16x8*)(H + (size_t)node * 96 + chunk * 8));
            bf16x8 o;
#pragma unroll
            for (int j = 0; j < 8; j++)
                o[j] = (short)ar1_f2b(acc[j] + di * di * ar1_b2f((unsigned short)hs[j]));
            *((bf16x8*)(AL + (size_t)wv * 104 + chunk * 8)) = o;
        }
    }
    __syncthreads();

    // ---- GEMM3: 96 -> 96, affine+ReLU (waves 0-5) ----
    if (wv < 6) {
        int t = wv;
        floatx4 g = (floatx4){0.f, 0.f, 0.f, 0.f};
#pragma unroll
        for (int c = 0; c < 3; c++) {
            bf16x8 a = *((const bf16x8*)(AL + (size_t)m * 104 + c * 32 + quad * 8));
            bf16x8 bfr = *((const bf16x8*)(b2w + ((size_t)(t * 3 + c) * 64 + lane) * 8));
            g = __builtin_amdgcn_mfma_f32_16x16x32_bf16(a, bfr, g, 0, 0, 0);
        }
#pragma unroll
        for (int r = 0; r < 4; r++) {
            int col = t * 16 + m;
            float v = g[r] * sc3[col] + sh3[col];
            H0[(quad * 4 + r) * 104 + col] = ar1_f2b(fmaxf(v, 0.f));
        }
    }
    __syncthreads();

    // ---- MLP L1: 96 -> 256 (+lb0, ReLU) (all 16 waves) ----
    {
        int t = wv;
        floatx4 g = (floatx4){0.f, 0.f, 0.f, 0.f};
#pragma unroll
        for (int c = 0; c < 3; c++) {
            bf16x8 a = *((const bf16x8*)(H0 + (size_t)m * 104 + c * 32 + quad * 8));
            bf16x8 bfr = *((const bf16x8*)(b3 + ((size_t)(t * 3 + c) * 64 + lane) * 8));
            g = __builtin_amdgcn_mfma_f32_16x16x32_bf16(a, bfr, g, 0, 0, 0);
        }
#pragma unroll
        for (int r = 0; r < 4; r++) {
            int col = t * 16 + m;
            H1[(quad * 4 + r) * 264 + col] = ar1_f2b(fmaxf(g[r] + lb0[col], 0.f));
        }
    }
    __syncthreads();

    // ---- MLP L2: 256 -> 128 (+lb1, ReLU) (waves 0-7) ----
    if (wv < 8) {
        int t = wv;
        floatx4 g = (floatx4){0.f, 0.f, 0.f, 0.f};
#pragma unroll
        for (int c = 0; c < 8; c++) {
            bf16x8 a = *((const bf16x8*)(H1 + (size_t)m * 264 + c * 32 + quad * 8));
            bf16x8 bfr = *((const bf16x8*)(b4 + ((size_t)(t * 8 + c) * 64 + lane) * 8));
            g = __builtin_amdgcn_mfma_f32_16x16x32_bf16(a, bfr, g, 0, 0, 0);
        }
#pragma unroll
        for (int r = 0; r < 4; r++) {
            int col = t * 16 + m;
            H2[(quad * 4 + r) * 136 + col] = ar1_f2b(fmaxf(g[r] + lb1[col], 0.f));
        }
    }
    __syncthreads();

    // ---- MLP L3: 128 -> 64 (+lb2, ReLU) (waves 0-3) ----
    if (wv < 4) {
        int t = wv;
        floatx4 g = (floatx4){0.f, 0.f, 0.f, 0.f};
#pragma unroll
        for (int c = 0; c < 4; c++) {
            bf16x8 a = *((const bf16x8*)(H2 + (size_t)m * 136 + c * 32 + quad * 8));
            bf16x8 bfr = *((const bf16x8*)(b5 + ((size_t)(t * 4 + c) * 64 + lane) * 8));
            g = __builtin_amdgcn_mfma_f32_16x16x32_bf16(a, bfr, g, 0, 0, 0);
        }
#pragma unroll
        for (int r = 0; r < 4; r++) {
            int col = t * 16 + m;
            H3[(quad * 4 + r) * 72 + col] = ar1_f2b(fmaxf(g[r] + lb2[col], 0.f));
        }
    }
    __syncthreads();

    // ---- MLP L4: 64 -> 8 (+lb3) (wave 0 -> out) ----
    if (wv == 0) {
        floatx4 g = (floatx4){0.f, 0.f, 0.f, 0.f};
#pragma unroll
        for (int c = 0; c < 2; c++) {
            bf16x8 a = *((const bf16x8*)(H3 + (size_t)m * 72 + c * 32 + quad * 8));
            bf16x8 bfr = *((const bf16x8*)(b6 + ((size_t)c * 64 + lane) * 8));
            g = __builtin_amdgcn_mfma_f32_16x16x32_bf16(a, bfr, g, 0, 0, 0);
        }
        int wf32 = f32out[0];
#pragma unroll
        for (int r = 0; r < 4; r++) {
            int row = nb + quad * 4 + r;
            if (m < 8) {
                float v = g[r] + lb3[m];
                if (wf32) ((float*)out)[(size_t)row * 8 + m] = v;
                else ((unsigned short*)out)[(size_t)row * 8 + m] = ar1_f2b(v);
            }
        }
    }
}

extern "C" void kernel_launch(void* const* d_in, const int* in_sizes, int n_in,
                              void* d_out, int out_size, void* d_ws, size_t ws_size,
                              hipStream_t stream) {
    (void)in_sizes; (void)n_in; (void)out_size;

    // workspace layout
    char* p = (char*)d_ws;
    unsigned short* bufA = (unsigned short*)p; p += (size_t)GN * 96 * 2;   // 9.6 MB
    unsigned short* bufB = (unsigned short*)p; p += (size_t)GN * 96 * 2;   // 9.6 MB
    unsigned int* pairs = (unsigned int*)p; p += (size_t)NPART * PSLOT * 4; // 3.6 MB
    int* indeg  = (int*)p;    p += (size_t)GN * 4;
    int* offs   = (int*)p;    p += (size_t)GN * 4;
    float* dinv = (float*)p;  p += (size_t)GN * 4;
    int* csr    = (int*)p;    p += (size_t)GE * 4;
    int* gcur   = (int*)p;    p += 1024;
    int* flagI  = (int*)p;    p += 1024;
    int* flagF  = (int*)p;    p += 1024;
    unsigned short* bpArena = (unsigned short*)p; p += 91136 * 2;  // packed W
    float* fArena = (float*)p; p += 2048 * 4;                      // small fp32
    size_t need = (size_t)(p - (char*)d_ws);
    if (ws_size < need) {
        hipMemsetAsync(d_out, 0x41, (size_t)GN * 8 * 2, stream);  // marker 12.06
        return;
    }

    // packed-weight arena offsets (shorts): w1,w2,w3,lw1,lw2,lw3,lw4
    unsigned short* bp[7];
    int bpn[7] = {6144, 9216, 9216, 24576, 32768, 8192, 1024};
    {
        unsigned short* q = bpArena;
        for (int i = 0; i < 7; i++) { bp[i] = q; q += bpn[i]; }
    }

    // small fp32 arena: lb1(256),lb2(128),lb3(64),lb4(8), 6 x 96 scale/shift
    float* lb[4]; float* ss[6];
    {
        float* q = fArena;
        int ln[4] = {256, 128, 64, 8};
        for (int i = 0; i < 4; i++) { lb[i] = q; q += ln[i]; }
        for (int i = 0; i < 6; i++) { ss[i] = q; q += 96; }
    }

    const int* ei = (const int*)d_in[1];
    const unsigned short* xw = (const unsigned short*)d_in[0];

    // graph build + weight prep: memset, merged kernel, csr
    hipMemsetAsync(gcur, 0, NPART * 4, stream);
    {
        PackAll pa;
        int wsrc[7] = {2, 6, 10, 14, 16, 18, 20};
        int Ks[7] = {64, 96, 96, 96, 256, 128, 64};
        int Ms[7] = {96, 96, 96, 256, 128, 64, 8};
        int cum = 0;
        for (int i = 0; i < 7; i++) {
            pa.src[i] = d_in[wsrc[i]]; pa.dst[i] = bp[i];
            pa.K[i] = Ks[i]; pa.M[i] = Ms[i];
            pa.start[i] = cum;
            cum += (Ms[i] + 15) / 16 * (Ks[i] / 32);
        }
        pa.start[7] = cum;   // 178
        SmallCvt sc;
        int lsrc[4] = {15, 17, 19, 21};
        int ln[4] = {256, 128, 64, 8};
        for (int i = 0; i < 4; i++) { sc.src[i] = d_in[lsrc[i]]; sc.dst[i] = lb[i]; sc.n[i] = ln[i]; }
        int gsrc[9] = {3, 4, 5, 7, 8, 9, 11, 12, 13};
        for (int i = 0; i < 9; i++) sc.gb[i] = d_in[gsrc[i]];
        for (int i = 0; i < 6; i++) sc.ss[i] = ss[i];
        Arthur1_16458314678864_kernel<<<437, 256, 0, stream>>>(
            pa, sc, ei, xw, flagI, flagF, gcur, pairs);
    }
    ar1_csr<<<NPART, 256, 0, stream>>>(pairs, gcur, csr, indeg, offs, dinv);

    const int FB = GN / 16;           // 3125 (fused kernels, 1024 thr)

    // GCN layers 1,2 fused agg+GEMM; layer 3 + GEMM3 + MLP in one kernel
    ar1_ag64g<<<FB, 1024, 0, stream>>>(d_in[0], offs, indeg, csr, dinv, flagF,
                                       bp[0], ss[0], ss[1], bufA);
    ar1_ag96g<<<FB, 1024, 0, stream>>>(bufA, offs, indeg, csr, dinv,
                                       bp[1], ss[2], ss[3], bufB);
    ar1_agmlp<<<FB, 1024, 0, stream>>>(bufB, offs, indeg, csr, dinv,
                                       bp[2], ss[4], ss[5],
                                       bp[3], bp[4], bp[5], bp[6],
                                       lb[0], lb[1], lb[2], lb[3], d_out, flagF);
}